// Round 7
// baseline (400.125 us; speedup 1.0000x reference)
//
#include <hip/hip_runtime.h>

#define DD 128
#define CHUNK 6144   // edges per block in S1/S3
#define NBMAX 512    // max buckets (N <= 65536)
#define SCAP 8192    // per-bucket LDS staging capacity

typedef __attribute__((ext_vector_type(8))) short bf16x8;
typedef __attribute__((ext_vector_type(4))) float f32x4;

// ---------- bf16 helpers ----------
__device__ __forceinline__ unsigned bf16rne(float f) {
  unsigned u = __float_as_uint(f);
  return (u + 0x7FFFu + ((u >> 16) & 1u)) >> 16;
}
__device__ __forceinline__ unsigned packbf(float lo, float hi) {
  return bf16rne(lo) | (bf16rne(hi) << 16);
}
__device__ __forceinline__ float bflo(unsigned v) { return __uint_as_float(v << 16); }
__device__ __forceinline__ float bfhi(unsigned v) { return __uint_as_float(v & 0xFFFF0000u); }

// ---------- inclusive block scan over LDS array (256 threads, nb <= 512) ----------
__device__ void block_scan_incl(int* cnt, int* inc, int nb, int tid) {
  for (int i = tid; i < nb; i += 256) inc[i] = cnt[i];
  __syncthreads();
  for (int d = 1; d < nb; d <<= 1) {
    int i0 = tid, i1 = tid + 256;
    int v0 = 0, v1 = 0;
    if (i0 < nb && i0 >= d) v0 = inc[i0 - d];
    if (i1 < nb && i1 >= d) v1 = inc[i1 - d];
    __syncthreads();
    if (i0 < nb) inc[i0] += v0;
    if (i1 < nb) inc[i1] += v1;
    __syncthreads();
  }
}

// ---------- S1: bucket histogram (bucket = dst >> 7) ----------
__global__ __launch_bounds__(256) void s1_hist(const int* __restrict__ dst,
                                               int* __restrict__ bucketCount, int e) {
  __shared__ int h[NBMAX];
  int tid = threadIdx.x;
  for (int i = tid; i < NBMAX; i += 256) h[i] = 0;
  __syncthreads();
  int i0 = blockIdx.x * CHUNK;
  int i1 = min(i0 + CHUNK, e);
  for (int i = i0 + tid; i < i1; i += 256) atomicAdd(&h[dst[i] >> 7], 1);
  __syncthreads();
  for (int i = tid; i < NBMAX; i += 256)
    if (h[i]) atomicAdd(&bucketCount[i], h[i]);
}

// ---------- S2: scan bucket counts ----------
__global__ __launch_bounds__(256) void s2_scan(const int* __restrict__ bucketCount,
                                               int* __restrict__ bucketOff,
                                               int* __restrict__ gCursor,
                                               int* __restrict__ rs, int nb, int n, int e) {
  __shared__ int cnt[NBMAX], inc[NBMAX];
  int tid = threadIdx.x;
  for (int i = tid; i < nb; i += 256) cnt[i] = bucketCount[i];
  __syncthreads();
  block_scan_incl(cnt, inc, nb, tid);
  for (int i = tid; i < nb; i += 256) {
    int off = inc[i] - cnt[i];
    bucketOff[i] = off;
    gCursor[i] = off;
  }
  if (tid == 0) { bucketOff[nb] = e; rs[n] = e; }
}

// ---------- S3: block-local grouping + coalesced bucket scatter ----------
__global__ __launch_bounds__(256) void s3_scatter(const int* __restrict__ src,
                                                  const int* __restrict__ dst,
                                                  int* __restrict__ gCursor,
                                                  unsigned int* __restrict__ bucketed,
                                                  int e, int nb) {
  __shared__ int cnt[NBMAX], inc[NBMAX], base[NBMAX], cur[NBMAX];
  __shared__ unsigned int pairs[CHUNK];
  int tid = threadIdx.x;
  for (int i = tid; i < nb; i += 256) cnt[i] = 0;
  __syncthreads();
  int i0 = blockIdx.x * CHUNK;
  int i1 = min(i0 + CHUNK, e);
  for (int i = i0 + tid; i < i1; i += 256) atomicAdd(&cnt[dst[i] >> 7], 1);
  __syncthreads();
  block_scan_incl(cnt, inc, nb, tid);
  for (int b = tid; b < nb; b += 256) {
    int c = cnt[b];
    base[b] = c ? atomicAdd(&gCursor[b], c) : 0;
    cur[b] = inc[b] - c;
  }
  __syncthreads();
  for (int i = i0 + tid; i < i1; i += 256) {
    int d = dst[i];
    int p = atomicAdd(&cur[d >> 7], 1);
    pairs[p] = (unsigned)d | ((unsigned)src[i] << 16);
  }
  __syncthreads();
  int m = i1 - i0;
  for (int i = tid; i < m; i += 256) {
    unsigned w = pairs[i];
    int b = (int)(w & 0xFFFFu) >> 7;
    bucketed[base[b] + (i - (inc[b] - cnt[b]))] = w;
  }
}

// ---------- S4: per-bucket node-level fill; emits rs[] and u16 ssrc ----------
__global__ __launch_bounds__(256) void s4_fill(const unsigned int* __restrict__ bucketed,
                                               const int* __restrict__ bucketOff,
                                               int* __restrict__ rs,
                                               unsigned short* __restrict__ ssrc, int n) {
  __shared__ int cnt[128], inc[128], cur[128];
  __shared__ unsigned short outb[SCAP];
  int b = blockIdx.x;
  int bo = bucketOff[b], b1 = bucketOff[b + 1];
  int len = b1 - bo;
  int tid = threadIdx.x;
  int n0 = b << 7;
  if (tid < 128) cnt[tid] = 0;
  __syncthreads();
  for (int i = tid; i < len; i += 256) atomicAdd(&cnt[bucketed[bo + i] & 127], 1);
  __syncthreads();
  if (tid < 128) inc[tid] = cnt[tid];
  __syncthreads();
  for (int d = 1; d < 128; d <<= 1) {
    int v = 0;
    if (tid < 128 && tid >= d) v = inc[tid - d];
    __syncthreads();
    if (tid < 128) inc[tid] += v;
    __syncthreads();
  }
  if (tid < 128) {
    int off = inc[tid] - cnt[tid];
    cur[tid] = off;
    int node = n0 + tid;
    if (node < n) rs[node] = bo + off;
  }
  __syncthreads();
  if (len <= SCAP) {
    for (int i = tid; i < len; i += 256) {
      unsigned w = bucketed[bo + i];
      int p = atomicAdd(&cur[w & 127], 1);
      outb[p] = (unsigned short)(w >> 16);
    }
    __syncthreads();
    for (int i = tid; i < len; i += 256) ssrc[bo + i] = outb[i];
  } else {
    for (int i = tid; i < len; i += 256) {
      unsigned w = bucketed[bo + i];
      int p = atomicAdd(&cur[w & 127], 1);
      ssrc[bo + p] = (unsigned short)(w >> 16);
    }
  }
}

// ---------- conv: f32 -> packed bf16x2, plus zero row at node N ----------
__global__ __launch_bounds__(256) void conv_bf16(const float* __restrict__ x,
                                                 unsigned int* __restrict__ hb,
                                                 int n64, int total64) {
  int i = blockIdx.x * 256 + threadIdx.x;
  if (i < n64) {
    float2 v = ((const float2*)x)[i];
    hb[i] = packbf(v.x, v.y);
  } else if (i < total64) {
    hb[i] = 0u;  // zero row used by gather tail slots
  }
}

// ---------- W prep: split W into (hi, lo) bf16, PRE-SWIZZLED [col][k] image ----------
__global__ __launch_bounds__(256) void prep_w(const float* __restrict__ W1,
                                              const float* __restrict__ W2,
                                              short* __restrict__ wt) {
  int idx = blockIdx.x * 256 + threadIdx.x;  // 3*2*16384
  if (idx >= 3 * 2 * 16384) return;
  int lm = idx >> 14;      // layer*2 + mat
  int e = idx & 16383;
  int k = e >> 7;
  int col = e & 127;
  int layer = lm >> 1, mat = lm & 1;
  const float* W = mat ? W2 : W1;
  float w = W[layer * 16384 + k * 128 + col];
  unsigned short h = (unsigned short)bf16rne(w);
  float hv = __uint_as_float((unsigned)h << 16);
  unsigned short lo = (unsigned short)bf16rne(w - hv);
  size_t base = (size_t)lm * 2 * 16384;
  int ksw = k ^ ((col & 7) << 3);  // swizzled k position
  wt[base + col * 128 + ksw] = (short)h;
  wt[base + 16384 + col * 128 + ksw] = (short)lo;
}

// ---------- aggregation: 4 edges per wave-instr, uint4 lanes, depth-8 pipeline ----------
// 16 lanes per edge-slot g=lane>>4; lane loads uint4 (16B) -> one dwordx4 per edge.
// Tail slots read the zero row hb[n]. Epilogue: shfl_xor tree over the 4 slots.
__global__ __launch_bounds__(256) void gather_zb(const unsigned int* __restrict__ hb,
                                                 const int* __restrict__ rs,
                                                 const unsigned short* __restrict__ ssrc,
                                                 unsigned int* __restrict__ zb, int n) {
  int node = blockIdx.x * 4 + (threadIdx.x >> 6);
  if (node >= n) return;
  int lane = threadIdx.x & 63;
  int g = lane >> 4;   // edge slot 0..3
  int cq = lane & 15;  // uint4 index within row (16 uint4 = 256B)
  int s0 = rs[node], s1 = rs[node + 1];
  int last = s1 - 1;
  int lastc = max(last, 0);
  const uint4* hb4 = (const uint4*)hb;

  // self term: slot 0 reads the node's row, slots 1-3 read the zero row
  uint4 sv = hb4[(unsigned)(g == 0 ? node : n) * 16u + cq];
  float acc[8];
  acc[0] = bflo(sv.x); acc[1] = bfhi(sv.x);
  acc[2] = bflo(sv.y); acc[3] = bfhi(sv.y);
  acc[4] = bflo(sv.z); acc[5] = bfhi(sv.z);
  acc[6] = bflo(sv.w); acc[7] = bfhi(sv.w);

  uint4 A[8], B[8];
#pragma unroll
  for (int i = 0; i < 8; ++i) {
    int t = s0 + i * 4 + g;
    int idx = (t <= last) ? (int)ssrc[min(t, lastc)] : n;
    A[i] = hb4[(unsigned)idx * 16u + cq];
  }
  for (int t0 = s0 + 32; t0 < s1; t0 += 32) {
    // issue next 32 edges
#pragma unroll
    for (int i = 0; i < 8; ++i) {
      int t = t0 + i * 4 + g;
      int idx = (t <= last) ? (int)ssrc[min(t, lastc)] : n;
      B[i] = hb4[(unsigned)idx * 16u + cq];
    }
    // accumulate current 32 edges
#pragma unroll
    for (int i = 0; i < 8; ++i) {
      acc[0] += bflo(A[i].x); acc[1] += bfhi(A[i].x);
      acc[2] += bflo(A[i].y); acc[3] += bfhi(A[i].y);
      acc[4] += bflo(A[i].z); acc[5] += bfhi(A[i].z);
      acc[6] += bflo(A[i].w); acc[7] += bfhi(A[i].w);
    }
#pragma unroll
    for (int i = 0; i < 8; ++i) A[i] = B[i];
  }
#pragma unroll
  for (int i = 0; i < 8; ++i) {
    acc[0] += bflo(A[i].x); acc[1] += bfhi(A[i].x);
    acc[2] += bflo(A[i].y); acc[3] += bfhi(A[i].y);
    acc[4] += bflo(A[i].z); acc[5] += bfhi(A[i].z);
    acc[6] += bflo(A[i].w); acc[7] += bfhi(A[i].w);
  }
  // combine the 4 edge-slots (lanes cq, cq+16, cq+32, cq+48)
#pragma unroll
  for (int i = 0; i < 8; ++i) {
    acc[i] += __shfl_xor(acc[i], 16, 64);
    acc[i] += __shfl_xor(acc[i], 32, 64);
  }
  if (g == 0) {
    uint4 o;
    o.x = packbf(acc[0], acc[1]);
    o.y = packbf(acc[2], acc[3]);
    o.z = packbf(acc[4], acc[5]);
    o.w = packbf(acc[6], acc[7]);
    ((uint4*)zb)[(unsigned)node * 16u + cq] = o;
  }
}

// ---------- MFMA MLP: hout = relu(z@W1+b1)@W2+b2 ----------
// 256 threads = 4 waves in 2x2: wave w -> rows (w&1)*64..+64, cols (w>>1)*64..+64.
__global__ __launch_bounds__(256, 2) void mlp_mfma(
    const unsigned int* __restrict__ zb,
    const short* __restrict__ Wt1, const short* __restrict__ Wt2,
    const float* __restrict__ b1, const float* __restrict__ b2,
    float* __restrict__ fout, unsigned short* __restrict__ hbout, int n) {
  __shared__ char wbuf[32768];      // one weight part (swizzled image)
  __shared__ char hsb[128 * 256];   // 32KB swizzled bf16 h-tile
  int tid = threadIdx.x;
  int w = tid >> 6, lane = tid & 63;
  int lr = lane & 15, hi = lane >> 4;
  int wr = (w & 1) * 64;
  int wc = (w >> 1) * 64;
  int node0 = blockIdx.x * 128;

  bf16x8 a[4][4];
#pragma unroll
  for (int t = 0; t < 4; ++t) {
    int row = node0 + wr + t * 16 + lr;
    row = min(row, n - 1);
    const char* rp = (const char*)(zb + (size_t)row * 64);
#pragma unroll
    for (int ks = 0; ks < 4; ++ks)
      a[t][ks] = *(const bf16x8*)(rp + ks * 64 + hi * 16);
  }

  f32x4 acc[4][4];
#pragma unroll
  for (int ct = 0; ct < 4; ++ct) {
    float bb = b1[wc + ct * 16 + lr];
#pragma unroll
    for (int t = 0; t < 4; ++t) acc[t][ct] = (f32x4){bb, bb, bb, bb};
  }

#pragma unroll
  for (int p = 0; p < 2; ++p) {
    __syncthreads();
    {
      const char* gs = (const char*)(Wt1 + p * 16384);
      for (int i = tid * 16; i < 32768; i += 256 * 16)
        *(float4*)&wbuf[i] = *(const float4*)(gs + i);
    }
    __syncthreads();
#pragma unroll
    for (int ct = 0; ct < 4; ++ct) {
      int col = wc + ct * 16 + lr;
      int cx = (col & 7) << 4;
#pragma unroll
      for (int ks = 0; ks < 4; ++ks) {
        bf16x8 b = *(const bf16x8*)&wbuf[(col * 256 + ks * 64 + hi * 16) ^ cx];
#pragma unroll
        for (int t = 0; t < 4; ++t)
          acc[t][ct] = __builtin_amdgcn_mfma_f32_16x16x32_bf16(a[t][ks], b, acc[t][ct], 0, 0, 0);
      }
    }
  }

#pragma unroll
  for (int t = 0; t < 4; ++t)
#pragma unroll
    for (int ct = 0; ct < 4; ++ct)
#pragma unroll
      for (int r = 0; r < 4; ++r) {
        int row = wr + t * 16 + hi * 4 + r;
        int col = wc + ct * 16 + lr;
        float v = fmaxf(acc[t][ct][r], 0.f);
        int byte = (row * 256 + col * 2) ^ ((row & 7) << 4);
        *(unsigned short*)&hsb[byte] = (unsigned short)bf16rne(v);
      }
  __syncthreads();

  bf16x8 a2[4][4];
#pragma unroll
  for (int t = 0; t < 4; ++t) {
    int row = wr + t * 16 + lr;
    int xr = (row & 7) << 4;
#pragma unroll
    for (int ks = 0; ks < 4; ++ks)
      a2[t][ks] = *(const bf16x8*)&hsb[(row * 256 + ks * 64 + hi * 16) ^ xr];
  }

#pragma unroll
  for (int ct = 0; ct < 4; ++ct) {
    float bb = b2[wc + ct * 16 + lr];
#pragma unroll
    for (int t = 0; t < 4; ++t) acc[t][ct] = (f32x4){bb, bb, bb, bb};
  }

#pragma unroll
  for (int p = 0; p < 2; ++p) {
    __syncthreads();
    {
      const char* gs = (const char*)(Wt2 + p * 16384);
      for (int i = tid * 16; i < 32768; i += 256 * 16)
        *(float4*)&wbuf[i] = *(const float4*)(gs + i);
    }
    __syncthreads();
#pragma unroll
    for (int ct = 0; ct < 4; ++ct) {
      int col = wc + ct * 16 + lr;
      int cx = (col & 7) << 4;
#pragma unroll
      for (int ks = 0; ks < 4; ++ks) {
        bf16x8 b = *(const bf16x8*)&wbuf[(col * 256 + ks * 64 + hi * 16) ^ cx];
#pragma unroll
        for (int t = 0; t < 4; ++t)
          acc[t][ct] = __builtin_amdgcn_mfma_f32_16x16x32_bf16(a2[t][ks], b, acc[t][ct], 0, 0, 0);
      }
    }
  }

#pragma unroll
  for (int t = 0; t < 4; ++t)
#pragma unroll
    for (int ct = 0; ct < 4; ++ct)
#pragma unroll
      for (int r = 0; r < 4; ++r) {
        int node = node0 + wr + t * 16 + hi * 4 + r;
        if (node < n) {
          int col = wc + ct * 16 + lr;
          float v = acc[t][ct][r];
          if (fout) fout[(size_t)node * DD + col] = v;
          if (hbout) hbout[(size_t)node * DD + col] = (unsigned short)bf16rne(v);
        }
      }
}

// ---------- classifier ----------
__global__ __launch_bounds__(256) void classifier_k(const float* __restrict__ h,
                                                    const float* __restrict__ Wc,
                                                    const float* __restrict__ bc,
                                                    float* __restrict__ out, int n) {
  __shared__ float wcs[DD * 16];
  for (int i = threadIdx.x; i < DD * 16; i += 256) wcs[i] = Wc[i];
  __syncthreads();
  int t = blockIdx.x * 256 + threadIdx.x;
  int node = t >> 4, c = t & 15;
  if (node >= n) return;
  float acc = bc[c];
  const float* hr = h + (size_t)node * DD;
#pragma unroll 8
  for (int k = 0; k < DD; ++k) acc += hr[k] * wcs[k * 16 + c];
  out[(size_t)node * 16 + c] = acc;
}

extern "C" void kernel_launch(void* const* d_in, const int* in_sizes, int n_in,
                              void* d_out, int out_size, void* d_ws, size_t ws_size,
                              hipStream_t stream) {
  const float* x = (const float*)d_in[0];
  const int* ei = (const int*)d_in[1];
  const float* W1 = (const float*)d_in[2];
  const float* b1 = (const float*)d_in[3];
  const float* W2 = (const float*)d_in[4];
  const float* b2 = (const float*)d_in[5];
  const float* Wc = (const float*)d_in[6];
  const float* bc = (const float*)d_in[7];

  const int N = in_sizes[0] / DD;
  const int E = in_sizes[1] / 2;
  const int* src = ei;
  const int* dst = ei + E;
  const int NB = (N + 127) >> 7;

  float* outp = (float*)d_out;
  float* h_final = outp;
  float* logits = outp + (size_t)N * DD;

  char* ws = (char*)d_ws;
  size_t off = 0;
  auto alloc = [&](size_t bytes) {
    char* p = ws + off;
    off = (off + bytes + 255) & ~(size_t)255;
    return p;
  };
  unsigned int* zb = (unsigned int*)alloc((size_t)N * 64 * 4);        // packed bf16 z
  unsigned int* hb = (unsigned int*)alloc((size_t)(N + 1) * 64 * 4);  // packed bf16 h + zero row
  short* wt = (short*)alloc((size_t)3 * 2 * 2 * 16384 * 2);           // split swizzled W
  int* bucketCount = (int*)alloc(NBMAX * 4);
  int* bucketOff = (int*)alloc((NBMAX + 1) * 4);
  int* gCursor = (int*)alloc(NBMAX * 4);
  int* rs = (int*)alloc((size_t)(N + 1) * 4);
  unsigned int* bucketed = (unsigned int*)alloc((size_t)E * 4);
  unsigned short* ssrc = (unsigned short*)alloc((size_t)E * 2);

  const int gEdge = (E + CHUNK - 1) / CHUNK;
  const int gGather = (N + 3) / 4;
  const int gMlp = (N + 127) / 128;
  const int total64 = (N + 1) * 64;

  // CSR build
  hipMemsetAsync(bucketCount, 0, NBMAX * 4, stream);
  s1_hist<<<gEdge, 256, 0, stream>>>(dst, bucketCount, E);
  s2_scan<<<1, 256, 0, stream>>>(bucketCount, bucketOff, gCursor, rs, NB, N, E);
  s3_scatter<<<gEdge, 256, 0, stream>>>(src, dst, gCursor, bucketed, E, NB);
  s4_fill<<<NB, 256, 0, stream>>>(bucketed, bucketOff, rs, ssrc, N);

  // weight prep + x -> bf16 (+ zero row)
  prep_w<<<(3 * 2 * 16384 + 255) / 256, 256, 0, stream>>>(W1, W2, wt);
  conv_bf16<<<(total64 + 255) / 256, 256, 0, stream>>>(x, hb, N * 64, total64);

  auto WT = [&](int layer, int mat) { return wt + ((size_t)(layer * 2 + mat)) * 2 * 16384; };

  // layer 0
  gather_zb<<<gGather, 256, 0, stream>>>(hb, rs, ssrc, zb, N);
  mlp_mfma<<<gMlp, 256, 0, stream>>>(zb, WT(0, 0), WT(0, 1), b1, b2,
                                     nullptr, (unsigned short*)hb, N);
  // layer 1
  gather_zb<<<gGather, 256, 0, stream>>>(hb, rs, ssrc, zb, N);
  mlp_mfma<<<gMlp, 256, 0, stream>>>(zb, WT(1, 0), WT(1, 1), b1 + DD, b2 + DD,
                                     nullptr, (unsigned short*)hb, N);
  // layer 2 -> f32 output
  gather_zb<<<gGather, 256, 0, stream>>>(hb, rs, ssrc, zb, N);
  mlp_mfma<<<gMlp, 256, 0, stream>>>(zb, WT(2, 0), WT(2, 1), b1 + 2 * DD, b2 + 2 * DD,
                                     h_final, nullptr, N);

  classifier_k<<<(N * 16 + 255) / 256, 256, 0, stream>>>(h_final, Wc, bc, logits, N);
}

// Round 8
// 321.203 us; speedup vs baseline: 1.2457x; 1.2457x over previous
//
#include <hip/hip_runtime.h>

#define DD 128
#define CHUNK 6144   // edges per block in S1/S3
#define NBMAX 512    // max buckets (N <= 65536)
#define SCAP 8192    // per-bucket LDS staging capacity (padded len mean ~4550, max ~5600)
#define PADSLACK 1024  // max padding per bucket (128 nodes x 8)

typedef __attribute__((ext_vector_type(8))) short bf16x8;
typedef __attribute__((ext_vector_type(4))) float f32x4;

// ---------- bf16 helpers ----------
__device__ __forceinline__ unsigned bf16rne(float f) {
  unsigned u = __float_as_uint(f);
  return (u + 0x7FFFu + ((u >> 16) & 1u)) >> 16;
}
__device__ __forceinline__ unsigned packbf(float lo, float hi) {
  return bf16rne(lo) | (bf16rne(hi) << 16);
}
__device__ __forceinline__ float bflo(unsigned v) { return __uint_as_float(v << 16); }
__device__ __forceinline__ float bfhi(unsigned v) { return __uint_as_float(v & 0xFFFF0000u); }

// ---------- inclusive block scan over LDS array (256 threads, nb <= 512) ----------
__device__ void block_scan_incl(int* cnt, int* inc, int nb, int tid) {
  for (int i = tid; i < nb; i += 256) inc[i] = cnt[i];
  __syncthreads();
  for (int d = 1; d < nb; d <<= 1) {
    int i0 = tid, i1 = tid + 256;
    int v0 = 0, v1 = 0;
    if (i0 < nb && i0 >= d) v0 = inc[i0 - d];
    if (i1 < nb && i1 >= d) v1 = inc[i1 - d];
    __syncthreads();
    if (i0 < nb) inc[i0] += v0;
    if (i1 < nb) inc[i1] += v1;
    __syncthreads();
  }
}

// ---------- S1: bucket histogram (bucket = dst >> 7) ----------
__global__ __launch_bounds__(256) void s1_hist(const int* __restrict__ dst,
                                               int* __restrict__ bucketCount, int e) {
  __shared__ int h[NBMAX];
  int tid = threadIdx.x;
  for (int i = tid; i < NBMAX; i += 256) h[i] = 0;
  __syncthreads();
  int i0 = blockIdx.x * CHUNK;
  int i1 = min(i0 + CHUNK, e);
  for (int i = i0 + tid; i < i1; i += 256) atomicAdd(&h[dst[i] >> 7], 1);
  __syncthreads();
  for (int i = tid; i < NBMAX; i += 256)
    if (h[i]) atomicAdd(&bucketCount[i], h[i]);
}

// ---------- S2: scan bucket counts ----------
__global__ __launch_bounds__(256) void s2_scan(const int* __restrict__ bucketCount,
                                               int* __restrict__ bucketOff,
                                               int* __restrict__ gCursor,
                                               int* __restrict__ rs, int nb, int n, int e) {
  __shared__ int cnt[NBMAX], inc[NBMAX];
  int tid = threadIdx.x;
  for (int i = tid; i < nb; i += 256) cnt[i] = bucketCount[i];
  __syncthreads();
  block_scan_incl(cnt, inc, nb, tid);
  for (int i = tid; i < nb; i += 256) {
    int off = inc[i] - cnt[i];
    bucketOff[i] = off;
    gCursor[i] = off;
  }
  if (tid == 0) { bucketOff[nb] = e; rs[n] = e; }
}

// ---------- S3: block-local grouping + coalesced bucket scatter ----------
__global__ __launch_bounds__(256) void s3_scatter(const int* __restrict__ src,
                                                  const int* __restrict__ dst,
                                                  int* __restrict__ gCursor,
                                                  unsigned int* __restrict__ bucketed,
                                                  int e, int nb) {
  __shared__ int cnt[NBMAX], inc[NBMAX], base[NBMAX], cur[NBMAX];
  __shared__ unsigned int pairs[CHUNK];
  int tid = threadIdx.x;
  for (int i = tid; i < nb; i += 256) cnt[i] = 0;
  __syncthreads();
  int i0 = blockIdx.x * CHUNK;
  int i1 = min(i0 + CHUNK, e);
  for (int i = i0 + tid; i < i1; i += 256) atomicAdd(&cnt[dst[i] >> 7], 1);
  __syncthreads();
  block_scan_incl(cnt, inc, nb, tid);
  for (int b = tid; b < nb; b += 256) {
    int c = cnt[b];
    base[b] = c ? atomicAdd(&gCursor[b], c) : 0;
    cur[b] = inc[b] - c;
  }
  __syncthreads();
  for (int i = i0 + tid; i < i1; i += 256) {
    int d = dst[i];
    int p = atomicAdd(&cur[d >> 7], 1);
    pairs[p] = (unsigned)d | ((unsigned)src[i] << 16);
  }
  __syncthreads();
  int m = i1 - i0;
  for (int i = tid; i < m; i += 256) {
    unsigned w = pairs[i];
    int b = (int)(w & 0xFFFFu) >> 7;
    bucketed[base[b] + (i - (inc[b] - cnt[b]))] = w;
  }
}

// ---------- S4: per-bucket fill of PADDED ssrc; emits rs[] (padded start) + pdeg ----------
// Node segments padded to multiple of 8 (min 8) with index n (zero row).
// Padded bucket base = bucketOff[b] + b*PADSLACK (slack bound: 128 nodes x 8).
__global__ __launch_bounds__(256) void s4_fill(const unsigned int* __restrict__ bucketed,
                                               const int* __restrict__ bucketOff,
                                               int* __restrict__ rs,
                                               unsigned short* __restrict__ pdeg,
                                               unsigned short* __restrict__ ssrc, int n) {
  __shared__ int cnt[128], pin[128], cur[128];
  __shared__ unsigned short outb[SCAP];
  int b = blockIdx.x;
  int bo = bucketOff[b], b1 = bucketOff[b + 1];
  int len = b1 - bo;
  int pstart = bo + b * PADSLACK;
  int tid = threadIdx.x;
  int n0 = b << 7;
  if (tid < 128) cnt[tid] = 0;
  __syncthreads();
  for (int i = tid; i < len; i += 256) atomicAdd(&cnt[bucketed[bo + i] & 127], 1);
  __syncthreads();
  int pc = 0;
  if (tid < 128) {
    pc = max(8, (cnt[tid] + 7) & ~7);
    pin[tid] = pc;
  }
  __syncthreads();
  for (int d = 1; d < 128; d <<= 1) {
    int v = 0;
    if (tid < 128 && tid >= d) v = pin[tid - d];
    __syncthreads();
    if (tid < 128) pin[tid] += v;
    __syncthreads();
  }
  int plen = pin[127];  // total padded length of this bucket
  if (tid < 128) {
    int off = pin[tid] - pc;
    cur[tid] = off;
    int node = n0 + tid;
    if (node < n) {
      rs[node] = pstart + off;
      pdeg[node] = (unsigned short)pc;
    }
  }
  __syncthreads();
  if (plen <= SCAP) {
    for (int i = tid; i < plen; i += 256) outb[i] = (unsigned short)n;
    __syncthreads();
    for (int i = tid; i < len; i += 256) {
      unsigned w = bucketed[bo + i];
      int p = atomicAdd(&cur[w & 127], 1);
      outb[p] = (unsigned short)(w >> 16);
    }
    __syncthreads();
    for (int i = tid; i < plen; i += 256) ssrc[pstart + i] = outb[i];  // coalesced
  } else {  // fallback (statistically unreachable)
    for (int i = tid; i < plen; i += 256) ssrc[pstart + i] = (unsigned short)n;
    __syncthreads();
    for (int i = tid; i < len; i += 256) {
      unsigned w = bucketed[bo + i];
      int p = atomicAdd(&cur[w & 127], 1);
      ssrc[pstart + p] = (unsigned short)(w >> 16);
    }
  }
}

// ---------- conv: f32 -> packed bf16x2, plus zero row at node N ----------
__global__ __launch_bounds__(256) void conv_bf16(const float* __restrict__ x,
                                                 unsigned int* __restrict__ hb,
                                                 int n64, int total64) {
  int i = blockIdx.x * 256 + threadIdx.x;
  if (i < n64) {
    float2 v = ((const float2*)x)[i];
    hb[i] = packbf(v.x, v.y);
  } else if (i < total64) {
    hb[i] = 0u;  // zero row read by padded gather slots
  }
}

// ---------- W prep: split W into (hi, lo) bf16, PRE-SWIZZLED [col][k] image ----------
__global__ __launch_bounds__(256) void prep_w(const float* __restrict__ W1,
                                              const float* __restrict__ W2,
                                              short* __restrict__ wt) {
  int idx = blockIdx.x * 256 + threadIdx.x;  // 3*2*16384
  if (idx >= 3 * 2 * 16384) return;
  int lm = idx >> 14;      // layer*2 + mat
  int e = idx & 16383;
  int k = e >> 7;
  int col = e & 127;
  int layer = lm >> 1, mat = lm & 1;
  const float* W = mat ? W2 : W1;
  float w = W[layer * 16384 + k * 128 + col];
  unsigned short h = (unsigned short)bf16rne(w);
  float hv = __uint_as_float((unsigned)h << 16);
  unsigned short lo = (unsigned short)bf16rne(w - hv);
  size_t base = (size_t)lm * 2 * 16384;
  int ksw = k ^ ((col & 7) << 3);  // swizzled k position
  wt[base + col * 128 + ksw] = (short)h;
  wt[base + 16384 + col * 128 + ksw] = (short)lo;
}

// ---------- aggregation: strip-of-8 nodes per wave, depth-8 pipeline, padded CSR ----------
// Round-6 memory pattern (1 edge row per instruction, 64 lanes x 4B) kept.
// Per-wave setup (rs/pdeg) amortized over 8 nodes via lane-parallel load + shfl.
// No per-edge clamp: segments padded to multiple of 8 with zero-row index n.
__global__ __launch_bounds__(256) void gather_zb(const unsigned int* __restrict__ hb,
                                                 const int* __restrict__ rs,
                                                 const unsigned short* __restrict__ pdeg,
                                                 const unsigned short* __restrict__ ssrc,
                                                 unsigned int* __restrict__ zb, int n) {
  int wv = blockIdx.x * 4 + (threadIdx.x >> 6);
  int nodeBase = wv * 8;
  if (nodeBase >= n) return;
  int lane = threadIdx.x & 63;
  int myNode = nodeBase + (lane & 7);
  int myRs = 0, myPd = 0;
  if (myNode < n) {
    myRs = rs[myNode];
    myPd = pdeg[myNode];
  }
#pragma unroll 1
  for (int u = 0; u < 8; ++u) {
    int node = nodeBase + u;
    if (node >= n) break;
    int s0 = __shfl(myRs, u, 64);
    int m = __shfl(myPd, u, 64);
    unsigned v = hb[(unsigned)node * 64u + lane];
    float ax = bflo(v), ay = bfhi(v);
    unsigned A[8], B[8];
#pragma unroll
    for (int i = 0; i < 8; ++i)
      A[i] = hb[(unsigned)ssrc[s0 + i] * 64u + lane];
    int t1 = s0 + m;
    for (int t = s0 + 8; t < t1; t += 8) {
#pragma unroll
      for (int i = 0; i < 8; ++i)
        B[i] = hb[(unsigned)ssrc[t + i] * 64u + lane];
#pragma unroll
      for (int i = 0; i < 8; ++i) {
        ax += bflo(A[i]);
        ay += bfhi(A[i]);
      }
#pragma unroll
      for (int i = 0; i < 8; ++i) A[i] = B[i];
    }
#pragma unroll
    for (int i = 0; i < 8; ++i) {
      ax += bflo(A[i]);
      ay += bfhi(A[i]);
    }
    zb[(unsigned)node * 64u + lane] = packbf(ax, ay);
  }
}

// ---------- MFMA MLP: hout = relu(z@W1+b1)@W2+b2 ----------
// 256 threads = 4 waves in 2x2: wave w -> rows (w&1)*64..+64, cols (w>>1)*64..+64.
__global__ __launch_bounds__(256, 2) void mlp_mfma(
    const unsigned int* __restrict__ zb,
    const short* __restrict__ Wt1, const short* __restrict__ Wt2,
    const float* __restrict__ b1, const float* __restrict__ b2,
    float* __restrict__ fout, unsigned short* __restrict__ hbout, int n) {
  __shared__ char wbuf[32768];      // one weight part (swizzled image)
  __shared__ char hsb[128 * 256];   // 32KB swizzled bf16 h-tile
  int tid = threadIdx.x;
  int w = tid >> 6, lane = tid & 63;
  int lr = lane & 15, hi = lane >> 4;
  int wr = (w & 1) * 64;
  int wc = (w >> 1) * 64;
  int node0 = blockIdx.x * 128;

  bf16x8 a[4][4];
#pragma unroll
  for (int t = 0; t < 4; ++t) {
    int row = node0 + wr + t * 16 + lr;
    row = min(row, n - 1);
    const char* rp = (const char*)(zb + (size_t)row * 64);
#pragma unroll
    for (int ks = 0; ks < 4; ++ks)
      a[t][ks] = *(const bf16x8*)(rp + ks * 64 + hi * 16);
  }

  f32x4 acc[4][4];
#pragma unroll
  for (int ct = 0; ct < 4; ++ct) {
    float bb = b1[wc + ct * 16 + lr];
#pragma unroll
    for (int t = 0; t < 4; ++t) acc[t][ct] = (f32x4){bb, bb, bb, bb};
  }

#pragma unroll
  for (int p = 0; p < 2; ++p) {
    __syncthreads();
    {
      const char* gs = (const char*)(Wt1 + p * 16384);
      for (int i = tid * 16; i < 32768; i += 256 * 16)
        *(float4*)&wbuf[i] = *(const float4*)(gs + i);
    }
    __syncthreads();
#pragma unroll
    for (int ct = 0; ct < 4; ++ct) {
      int col = wc + ct * 16 + lr;
      int cx = (col & 7) << 4;
#pragma unroll
      for (int ks = 0; ks < 4; ++ks) {
        bf16x8 b = *(const bf16x8*)&wbuf[(col * 256 + ks * 64 + hi * 16) ^ cx];
#pragma unroll
        for (int t = 0; t < 4; ++t)
          acc[t][ct] = __builtin_amdgcn_mfma_f32_16x16x32_bf16(a[t][ks], b, acc[t][ct], 0, 0, 0);
      }
    }
  }

#pragma unroll
  for (int t = 0; t < 4; ++t)
#pragma unroll
    for (int ct = 0; ct < 4; ++ct)
#pragma unroll
      for (int r = 0; r < 4; ++r) {
        int row = wr + t * 16 + hi * 4 + r;
        int col = wc + ct * 16 + lr;
        float v = fmaxf(acc[t][ct][r], 0.f);
        int byte = (row * 256 + col * 2) ^ ((row & 7) << 4);
        *(unsigned short*)&hsb[byte] = (unsigned short)bf16rne(v);
      }
  __syncthreads();

  bf16x8 a2[4][4];
#pragma unroll
  for (int t = 0; t < 4; ++t) {
    int row = wr + t * 16 + lr;
    int xr = (row & 7) << 4;
#pragma unroll
    for (int ks = 0; ks < 4; ++ks)
      a2[t][ks] = *(const bf16x8*)&hsb[(row * 256 + ks * 64 + hi * 16) ^ xr];
  }

#pragma unroll
  for (int ct = 0; ct < 4; ++ct) {
    float bb = b2[wc + ct * 16 + lr];
#pragma unroll
    for (int t = 0; t < 4; ++t) acc[t][ct] = (f32x4){bb, bb, bb, bb};
  }

#pragma unroll
  for (int p = 0; p < 2; ++p) {
    __syncthreads();
    {
      const char* gs = (const char*)(Wt2 + p * 16384);
      for (int i = tid * 16; i < 32768; i += 256 * 16)
        *(float4*)&wbuf[i] = *(const float4*)(gs + i);
    }
    __syncthreads();
#pragma unroll
    for (int ct = 0; ct < 4; ++ct) {
      int col = wc + ct * 16 + lr;
      int cx = (col & 7) << 4;
#pragma unroll
      for (int ks = 0; ks < 4; ++ks) {
        bf16x8 b = *(const bf16x8*)&wbuf[(col * 256 + ks * 64 + hi * 16) ^ cx];
#pragma unroll
        for (int t = 0; t < 4; ++t)
          acc[t][ct] = __builtin_amdgcn_mfma_f32_16x16x32_bf16(a2[t][ks], b, acc[t][ct], 0, 0, 0);
      }
    }
  }

#pragma unroll
  for (int t = 0; t < 4; ++t)
#pragma unroll
    for (int ct = 0; ct < 4; ++ct)
#pragma unroll
      for (int r = 0; r < 4; ++r) {
        int node = node0 + wr + t * 16 + hi * 4 + r;
        if (node < n) {
          int col = wc + ct * 16 + lr;
          float v = acc[t][ct][r];
          if (fout) fout[(size_t)node * DD + col] = v;
          if (hbout) hbout[(size_t)node * DD + col] = (unsigned short)bf16rne(v);
        }
      }
}

// ---------- classifier ----------
__global__ __launch_bounds__(256) void classifier_k(const float* __restrict__ h,
                                                    const float* __restrict__ Wc,
                                                    const float* __restrict__ bc,
                                                    float* __restrict__ out, int n) {
  __shared__ float wcs[DD * 16];
  for (int i = threadIdx.x; i < DD * 16; i += 256) wcs[i] = Wc[i];
  __syncthreads();
  int t = blockIdx.x * 256 + threadIdx.x;
  int node = t >> 4, c = t & 15;
  if (node >= n) return;
  float acc = bc[c];
  const float* hr = h + (size_t)node * DD;
#pragma unroll 8
  for (int k = 0; k < DD; ++k) acc += hr[k] * wcs[k * 16 + c];
  out[(size_t)node * 16 + c] = acc;
}

extern "C" void kernel_launch(void* const* d_in, const int* in_sizes, int n_in,
                              void* d_out, int out_size, void* d_ws, size_t ws_size,
                              hipStream_t stream) {
  const float* x = (const float*)d_in[0];
  const int* ei = (const int*)d_in[1];
  const float* W1 = (const float*)d_in[2];
  const float* b1 = (const float*)d_in[3];
  const float* W2 = (const float*)d_in[4];
  const float* b2 = (const float*)d_in[5];
  const float* Wc = (const float*)d_in[6];
  const float* bc = (const float*)d_in[7];

  const int N = in_sizes[0] / DD;
  const int E = in_sizes[1] / 2;
  const int* src = ei;
  const int* dst = ei + E;
  const int NB = (N + 127) >> 7;

  float* outp = (float*)d_out;
  float* h_final = outp;
  float* logits = outp + (size_t)N * DD;

  char* ws = (char*)d_ws;
  size_t off = 0;
  auto alloc = [&](size_t bytes) {
    char* p = ws + off;
    off = (off + bytes + 255) & ~(size_t)255;
    return p;
  };
  unsigned int* zb = (unsigned int*)alloc((size_t)N * 64 * 4);        // packed bf16 z
  unsigned int* hb = (unsigned int*)alloc((size_t)(N + 1) * 64 * 4);  // packed bf16 h + zero row
  short* wt = (short*)alloc((size_t)3 * 2 * 2 * 16384 * 2);           // split swizzled W
  int* bucketCount = (int*)alloc(NBMAX * 4);
  int* bucketOff = (int*)alloc((NBMAX + 1) * 4);
  int* gCursor = (int*)alloc(NBMAX * 4);
  int* rs = (int*)alloc((size_t)(N + 1) * 4);
  unsigned short* pdeg = (unsigned short*)alloc((size_t)N * 2);
  unsigned int* bucketed = (unsigned int*)alloc((size_t)E * 4);
  unsigned short* ssrc = (unsigned short*)alloc(((size_t)E + (size_t)NB * PADSLACK) * 2);

  const int gEdge = (E + CHUNK - 1) / CHUNK;
  const int gGather = (N + 31) / 32;  // 32 nodes/block (8 per wave)
  const int gMlp = (N + 127) / 128;
  const int total64 = (N + 1) * 64;

  // CSR build (padded)
  hipMemsetAsync(bucketCount, 0, NBMAX * 4, stream);
  s1_hist<<<gEdge, 256, 0, stream>>>(dst, bucketCount, E);
  s2_scan<<<1, 256, 0, stream>>>(bucketCount, bucketOff, gCursor, rs, NB, N, E);
  s3_scatter<<<gEdge, 256, 0, stream>>>(src, dst, gCursor, bucketed, E, NB);
  s4_fill<<<NB, 256, 0, stream>>>(bucketed, bucketOff, rs, pdeg, ssrc, N);

  // weight prep + x -> bf16 (+ zero row)
  prep_w<<<(3 * 2 * 16384 + 255) / 256, 256, 0, stream>>>(W1, W2, wt);
  conv_bf16<<<(total64 + 255) / 256, 256, 0, stream>>>(x, hb, N * 64, total64);

  auto WT = [&](int layer, int mat) { return wt + ((size_t)(layer * 2 + mat)) * 2 * 16384; };

  // layer 0
  gather_zb<<<gGather, 256, 0, stream>>>(hb, rs, pdeg, ssrc, zb, N);
  mlp_mfma<<<gMlp, 256, 0, stream>>>(zb, WT(0, 0), WT(0, 1), b1, b2,
                                     nullptr, (unsigned short*)hb, N);
  // layer 1
  gather_zb<<<gGather, 256, 0, stream>>>(hb, rs, pdeg, ssrc, zb, N);
  mlp_mfma<<<gMlp, 256, 0, stream>>>(zb, WT(1, 0), WT(1, 1), b1 + DD, b2 + DD,
                                     nullptr, (unsigned short*)hb, N);
  // layer 2 -> f32 output
  gather_zb<<<gGather, 256, 0, stream>>>(hb, rs, pdeg, ssrc, zb, N);
  mlp_mfma<<<gMlp, 256, 0, stream>>>(zb, WT(2, 0), WT(2, 1), b1 + 2 * DD, b2 + 2 * DD,
                                     h_final, nullptr, N);

  classifier_k<<<(N * 16 + 255) / 256, 256, 0, stream>>>(h_final, Wc, bc, logits, N);
}

// Round 9
// 295.194 us; speedup vs baseline: 1.3555x; 1.0881x over previous
//
#include <hip/hip_runtime.h>

#define DD 128
#define CHUNK 6144   // edges per block in S1/S3
#define NBMAX 512    // max buckets (N <= 65536)
#define SCAP 8192    // per-bucket LDS staging capacity (padded len mean ~4550)
#define PADSLACK 1024  // max padding per bucket (128 nodes x 8)

typedef __attribute__((ext_vector_type(8))) short bf16x8;
typedef __attribute__((ext_vector_type(4))) float f32x4;

// ---------- bf16 helpers ----------
__device__ __forceinline__ unsigned bf16rne(float f) {
  unsigned u = __float_as_uint(f);
  return (u + 0x7FFFu + ((u >> 16) & 1u)) >> 16;
}
__device__ __forceinline__ unsigned packbf(float lo, float hi) {
  return bf16rne(lo) | (bf16rne(hi) << 16);
}
__device__ __forceinline__ float bflo(unsigned v) { return __uint_as_float(v << 16); }
__device__ __forceinline__ float bfhi(unsigned v) { return __uint_as_float(v & 0xFFFF0000u); }

// ---------- inclusive block scan over LDS array (256 threads, nb <= 512) ----------
__device__ void block_scan_incl(int* cnt, int* inc, int nb, int tid) {
  for (int i = tid; i < nb; i += 256) inc[i] = cnt[i];
  __syncthreads();
  for (int d = 1; d < nb; d <<= 1) {
    int i0 = tid, i1 = tid + 256;
    int v0 = 0, v1 = 0;
    if (i0 < nb && i0 >= d) v0 = inc[i0 - d];
    if (i1 < nb && i1 >= d) v1 = inc[i1 - d];
    __syncthreads();
    if (i0 < nb) inc[i0] += v0;
    if (i1 < nb) inc[i1] += v1;
    __syncthreads();
  }
}

// ---------- S1: bucket histogram (bucket = dst >> 7) ----------
__global__ __launch_bounds__(256) void s1_hist(const int* __restrict__ dst,
                                               int* __restrict__ bucketCount, int e) {
  __shared__ int h[NBMAX];
  int tid = threadIdx.x;
  for (int i = tid; i < NBMAX; i += 256) h[i] = 0;
  __syncthreads();
  int i0 = blockIdx.x * CHUNK;
  int i1 = min(i0 + CHUNK, e);
  for (int i = i0 + tid; i < i1; i += 256) atomicAdd(&h[dst[i] >> 7], 1);
  __syncthreads();
  for (int i = tid; i < NBMAX; i += 256)
    if (h[i]) atomicAdd(&bucketCount[i], h[i]);
}

// ---------- S2: scan bucket counts ----------
__global__ __launch_bounds__(256) void s2_scan(const int* __restrict__ bucketCount,
                                               int* __restrict__ bucketOff,
                                               int* __restrict__ gCursor,
                                               int* __restrict__ rs, int nb, int n, int e) {
  __shared__ int cnt[NBMAX], inc[NBMAX];
  int tid = threadIdx.x;
  for (int i = tid; i < nb; i += 256) cnt[i] = bucketCount[i];
  __syncthreads();
  block_scan_incl(cnt, inc, nb, tid);
  for (int i = tid; i < nb; i += 256) {
    int off = inc[i] - cnt[i];
    bucketOff[i] = off;
    gCursor[i] = off;
  }
  if (tid == 0) { bucketOff[nb] = e; rs[n] = e; }
}

// ---------- S3: block-local grouping + coalesced bucket scatter ----------
__global__ __launch_bounds__(256) void s3_scatter(const int* __restrict__ src,
                                                  const int* __restrict__ dst,
                                                  int* __restrict__ gCursor,
                                                  unsigned int* __restrict__ bucketed,
                                                  int e, int nb) {
  __shared__ int cnt[NBMAX], inc[NBMAX], base[NBMAX], cur[NBMAX];
  __shared__ unsigned int pairs[CHUNK];
  int tid = threadIdx.x;
  for (int i = tid; i < nb; i += 256) cnt[i] = 0;
  __syncthreads();
  int i0 = blockIdx.x * CHUNK;
  int i1 = min(i0 + CHUNK, e);
  for (int i = i0 + tid; i < i1; i += 256) atomicAdd(&cnt[dst[i] >> 7], 1);
  __syncthreads();
  block_scan_incl(cnt, inc, nb, tid);
  for (int b = tid; b < nb; b += 256) {
    int c = cnt[b];
    base[b] = c ? atomicAdd(&gCursor[b], c) : 0;
    cur[b] = inc[b] - c;
  }
  __syncthreads();
  for (int i = i0 + tid; i < i1; i += 256) {
    int d = dst[i];
    int p = atomicAdd(&cur[d >> 7], 1);
    pairs[p] = (unsigned)d | ((unsigned)src[i] << 16);
  }
  __syncthreads();
  int m = i1 - i0;
  for (int i = tid; i < m; i += 256) {
    unsigned w = pairs[i];
    int b = (int)(w & 0xFFFFu) >> 7;
    bucketed[base[b] + (i - (inc[b] - cnt[b]))] = w;
  }
}

// ---------- S4: per-bucket fill of PADDED ssrc; emits rs[] (padded start) + pdeg ----------
// Node segments padded to multiple of 8 (min 8) with index n (zero row).
__global__ __launch_bounds__(256) void s4_fill(const unsigned int* __restrict__ bucketed,
                                               const int* __restrict__ bucketOff,
                                               int* __restrict__ rs,
                                               unsigned short* __restrict__ pdeg,
                                               unsigned short* __restrict__ ssrc, int n) {
  __shared__ int cnt[128], pin[128], cur[128];
  __shared__ unsigned short outb[SCAP];
  int b = blockIdx.x;
  int bo = bucketOff[b], b1 = bucketOff[b + 1];
  int len = b1 - bo;
  int pstart = bo + b * PADSLACK;
  int tid = threadIdx.x;
  int n0 = b << 7;
  if (tid < 128) cnt[tid] = 0;
  __syncthreads();
  for (int i = tid; i < len; i += 256) atomicAdd(&cnt[bucketed[bo + i] & 127], 1);
  __syncthreads();
  int pc = 0;
  if (tid < 128) {
    pc = max(8, (cnt[tid] + 7) & ~7);
    pin[tid] = pc;
  }
  __syncthreads();
  for (int d = 1; d < 128; d <<= 1) {
    int v = 0;
    if (tid < 128 && tid >= d) v = pin[tid - d];
    __syncthreads();
    if (tid < 128) pin[tid] += v;
    __syncthreads();
  }
  int plen = pin[127];  // total padded length of this bucket
  if (tid < 128) {
    int off = pin[tid] - pc;
    cur[tid] = off;
    int node = n0 + tid;
    if (node < n) {
      rs[node] = pstart + off;
      pdeg[node] = (unsigned short)pc;
    }
  }
  __syncthreads();
  if (plen <= SCAP) {
    for (int i = tid; i < plen; i += 256) outb[i] = (unsigned short)n;
    __syncthreads();
    for (int i = tid; i < len; i += 256) {
      unsigned w = bucketed[bo + i];
      int p = atomicAdd(&cur[w & 127], 1);
      outb[p] = (unsigned short)(w >> 16);
    }
    __syncthreads();
    for (int i = tid; i < plen; i += 256) ssrc[pstart + i] = outb[i];  // coalesced
  } else {  // fallback (statistically unreachable)
    for (int i = tid; i < plen; i += 256) ssrc[pstart + i] = (unsigned short)n;
    __syncthreads();
    for (int i = tid; i < len; i += 256) {
      unsigned w = bucketed[bo + i];
      int p = atomicAdd(&cur[w & 127], 1);
      ssrc[pstart + p] = (unsigned short)(w >> 16);
    }
  }
}

// ---------- conv: f32 -> packed bf16x2, plus zero row at node N ----------
__global__ __launch_bounds__(256) void conv_bf16(const float* __restrict__ x,
                                                 unsigned int* __restrict__ hb,
                                                 int n64, int total64) {
  int i = blockIdx.x * 256 + threadIdx.x;
  if (i < n64) {
    float2 v = ((const float2*)x)[i];
    hb[i] = packbf(v.x, v.y);
  } else if (i < total64) {
    hb[i] = 0u;  // zero row read by padded gather slots
  }
}

// ---------- W prep: split W into (hi, lo) bf16, PRE-SWIZZLED [col][k] image ----------
__global__ __launch_bounds__(256) void prep_w(const float* __restrict__ W1,
                                              const float* __restrict__ W2,
                                              short* __restrict__ wt) {
  int idx = blockIdx.x * 256 + threadIdx.x;  // 3*2*16384
  if (idx >= 3 * 2 * 16384) return;
  int lm = idx >> 14;      // layer*2 + mat
  int e = idx & 16383;
  int k = e >> 7;
  int col = e & 127;
  int layer = lm >> 1, mat = lm & 1;
  const float* W = mat ? W2 : W1;
  float w = W[layer * 16384 + k * 128 + col];
  unsigned short h = (unsigned short)bf16rne(w);
  float hv = __uint_as_float((unsigned)h << 16);
  unsigned short lo = (unsigned short)bf16rne(w - hv);
  size_t base = (size_t)lm * 2 * 16384;
  int ksw = k ^ ((col & 7) << 3);  // swizzled k position
  wt[base + col * 128 + ksw] = (short)h;
  wt[base + 16384 + col * 128 + ksw] = (short)lo;
}

// ---------- aggregation: 1 node/wave (round-6 structure), depth-8, padded CSR ----------
// No per-edge clamp: segments are multiples of 8; pads point at zero row hb[n].
__global__ __launch_bounds__(256) void gather_zb(const unsigned int* __restrict__ hb,
                                                 const int* __restrict__ rs,
                                                 const unsigned short* __restrict__ pdeg,
                                                 const unsigned short* __restrict__ ssrc,
                                                 unsigned int* __restrict__ zb, int n) {
  int node = blockIdx.x * 4 + (threadIdx.x >> 6);
  if (node >= n) return;
  int lane = threadIdx.x & 63;
  int s0 = rs[node];
  int m = pdeg[node];
  unsigned v = hb[(unsigned)node * 64u + lane];
  float ax = bflo(v), ay = bfhi(v);
  unsigned A[8], B[8];
#pragma unroll
  for (int i = 0; i < 8; ++i)
    A[i] = hb[(unsigned)ssrc[s0 + i] * 64u + lane];
  int t1 = s0 + m;
  for (int t = s0 + 8; t < t1; t += 8) {
#pragma unroll
    for (int i = 0; i < 8; ++i)
      B[i] = hb[(unsigned)ssrc[t + i] * 64u + lane];
#pragma unroll
    for (int i = 0; i < 8; ++i) {
      ax += bflo(A[i]);
      ay += bfhi(A[i]);
    }
#pragma unroll
    for (int i = 0; i < 8; ++i) A[i] = B[i];
  }
#pragma unroll
  for (int i = 0; i < 8; ++i) {
    ax += bflo(A[i]);
    ay += bfhi(A[i]);
  }
  zb[(unsigned)node * 64u + lane] = packbf(ax, ay);
}

// ---------- MFMA MLP: hout = relu(z@W1+b1)@W2+b2 ----------
// 256 threads = 4 waves in 2x2: wave w -> rows (w&1)*64..+64, cols (w>>1)*64..+64.
__global__ __launch_bounds__(256, 2) void mlp_mfma(
    const unsigned int* __restrict__ zb,
    const short* __restrict__ Wt1, const short* __restrict__ Wt2,
    const float* __restrict__ b1, const float* __restrict__ b2,
    float* __restrict__ fout, unsigned short* __restrict__ hbout, int n) {
  __shared__ char wbuf[32768];      // one weight part (swizzled image)
  __shared__ char hsb[128 * 256];   // 32KB swizzled bf16 h-tile
  int tid = threadIdx.x;
  int w = tid >> 6, lane = tid & 63;
  int lr = lane & 15, hi = lane >> 4;
  int wr = (w & 1) * 64;
  int wc = (w >> 1) * 64;
  int node0 = blockIdx.x * 128;

  bf16x8 a[4][4];
#pragma unroll
  for (int t = 0; t < 4; ++t) {
    int row = node0 + wr + t * 16 + lr;
    row = min(row, n - 1);
    const char* rp = (const char*)(zb + (size_t)row * 64);
#pragma unroll
    for (int ks = 0; ks < 4; ++ks)
      a[t][ks] = *(const bf16x8*)(rp + ks * 64 + hi * 16);
  }

  f32x4 acc[4][4];
#pragma unroll
  for (int ct = 0; ct < 4; ++ct) {
    float bb = b1[wc + ct * 16 + lr];
#pragma unroll
    for (int t = 0; t < 4; ++t) acc[t][ct] = (f32x4){bb, bb, bb, bb};
  }

#pragma unroll
  for (int p = 0; p < 2; ++p) {
    __syncthreads();
    {
      const char* gs = (const char*)(Wt1 + p * 16384);
      for (int i = tid * 16; i < 32768; i += 256 * 16)
        *(float4*)&wbuf[i] = *(const float4*)(gs + i);
    }
    __syncthreads();
#pragma unroll
    for (int ct = 0; ct < 4; ++ct) {
      int col = wc + ct * 16 + lr;
      int cx = (col & 7) << 4;
#pragma unroll
      for (int ks = 0; ks < 4; ++ks) {
        bf16x8 b = *(const bf16x8*)&wbuf[(col * 256 + ks * 64 + hi * 16) ^ cx];
#pragma unroll
        for (int t = 0; t < 4; ++t)
          acc[t][ct] = __builtin_amdgcn_mfma_f32_16x16x32_bf16(a[t][ks], b, acc[t][ct], 0, 0, 0);
      }
    }
  }

#pragma unroll
  for (int t = 0; t < 4; ++t)
#pragma unroll
    for (int ct = 0; ct < 4; ++ct)
#pragma unroll
      for (int r = 0; r < 4; ++r) {
        int row = wr + t * 16 + hi * 4 + r;
        int col = wc + ct * 16 + lr;
        float v = fmaxf(acc[t][ct][r], 0.f);
        int byte = (row * 256 + col * 2) ^ ((row & 7) << 4);
        *(unsigned short*)&hsb[byte] = (unsigned short)bf16rne(v);
      }
  __syncthreads();

  bf16x8 a2[4][4];
#pragma unroll
  for (int t = 0; t < 4; ++t) {
    int row = wr + t * 16 + lr;
    int xr = (row & 7) << 4;
#pragma unroll
    for (int ks = 0; ks < 4; ++ks)
      a2[t][ks] = *(const bf16x8*)&hsb[(row * 256 + ks * 64 + hi * 16) ^ xr];
  }

#pragma unroll
  for (int ct = 0; ct < 4; ++ct) {
    float bb = b2[wc + ct * 16 + lr];
#pragma unroll
    for (int t = 0; t < 4; ++t) acc[t][ct] = (f32x4){bb, bb, bb, bb};
  }

#pragma unroll
  for (int p = 0; p < 2; ++p) {
    __syncthreads();
    {
      const char* gs = (const char*)(Wt2 + p * 16384);
      for (int i = tid * 16; i < 32768; i += 256 * 16)
        *(float4*)&wbuf[i] = *(const float4*)(gs + i);
    }
    __syncthreads();
#pragma unroll
    for (int ct = 0; ct < 4; ++ct) {
      int col = wc + ct * 16 + lr;
      int cx = (col & 7) << 4;
#pragma unroll
      for (int ks = 0; ks < 4; ++ks) {
        bf16x8 b = *(const bf16x8*)&wbuf[(col * 256 + ks * 64 + hi * 16) ^ cx];
#pragma unroll
        for (int t = 0; t < 4; ++t)
          acc[t][ct] = __builtin_amdgcn_mfma_f32_16x16x32_bf16(a2[t][ks], b, acc[t][ct], 0, 0, 0);
      }
    }
  }

#pragma unroll
  for (int t = 0; t < 4; ++t)
#pragma unroll
    for (int ct = 0; ct < 4; ++ct)
#pragma unroll
      for (int r = 0; r < 4; ++r) {
        int node = node0 + wr + t * 16 + hi * 4 + r;
        if (node < n) {
          int col = wc + ct * 16 + lr;
          float v = acc[t][ct][r];
          if (fout) fout[(size_t)node * DD + col] = v;
          if (hbout) hbout[(size_t)node * DD + col] = (unsigned short)bf16rne(v);
        }
      }
}

// ---------- classifier ----------
__global__ __launch_bounds__(256) void classifier_k(const float* __restrict__ h,
                                                    const float* __restrict__ Wc,
                                                    const float* __restrict__ bc,
                                                    float* __restrict__ out, int n) {
  __shared__ float wcs[DD * 16];
  for (int i = threadIdx.x; i < DD * 16; i += 256) wcs[i] = Wc[i];
  __syncthreads();
  int t = blockIdx.x * 256 + threadIdx.x;
  int node = t >> 4, c = t & 15;
  if (node >= n) return;
  float acc = bc[c];
  const float* hr = h + (size_t)node * DD;
#pragma unroll 8
  for (int k = 0; k < DD; ++k) acc += hr[k] * wcs[k * 16 + c];
  out[(size_t)node * 16 + c] = acc;
}

extern "C" void kernel_launch(void* const* d_in, const int* in_sizes, int n_in,
                              void* d_out, int out_size, void* d_ws, size_t ws_size,
                              hipStream_t stream) {
  const float* x = (const float*)d_in[0];
  const int* ei = (const int*)d_in[1];
  const float* W1 = (const float*)d_in[2];
  const float* b1 = (const float*)d_in[3];
  const float* W2 = (const float*)d_in[4];
  const float* b2 = (const float*)d_in[5];
  const float* Wc = (const float*)d_in[6];
  const float* bc = (const float*)d_in[7];

  const int N = in_sizes[0] / DD;
  const int E = in_sizes[1] / 2;
  const int* src = ei;
  const int* dst = ei + E;
  const int NB = (N + 127) >> 7;

  float* outp = (float*)d_out;
  float* h_final = outp;
  float* logits = outp + (size_t)N * DD;

  char* ws = (char*)d_ws;
  size_t off = 0;
  auto alloc = [&](size_t bytes) {
    char* p = ws + off;
    off = (off + bytes + 255) & ~(size_t)255;
    return p;
  };
  unsigned int* zb = (unsigned int*)alloc((size_t)N * 64 * 4);        // packed bf16 z
  unsigned int* hb = (unsigned int*)alloc((size_t)(N + 1) * 64 * 4);  // packed bf16 h + zero row
  short* wt = (short*)alloc((size_t)3 * 2 * 2 * 16384 * 2);           // split swizzled W
  int* bucketCount = (int*)alloc(NBMAX * 4);
  int* bucketOff = (int*)alloc((NBMAX + 1) * 4);
  int* gCursor = (int*)alloc(NBMAX * 4);
  int* rs = (int*)alloc((size_t)(N + 1) * 4);
  unsigned short* pdeg = (unsigned short*)alloc((size_t)N * 2);
  unsigned int* bucketed = (unsigned int*)alloc((size_t)E * 4);
  unsigned short* ssrc = (unsigned short*)alloc(((size_t)E + (size_t)NB * PADSLACK) * 2);

  const int gEdge = (E + CHUNK - 1) / CHUNK;
  const int gGather = (N + 3) / 4;  // 4 nodes/block, 1 per wave
  const int gMlp = (N + 127) / 128;
  const int total64 = (N + 1) * 64;

  // CSR build (padded)
  hipMemsetAsync(bucketCount, 0, NBMAX * 4, stream);
  s1_hist<<<gEdge, 256, 0, stream>>>(dst, bucketCount, E);
  s2_scan<<<1, 256, 0, stream>>>(bucketCount, bucketOff, gCursor, rs, NB, N, E);
  s3_scatter<<<gEdge, 256, 0, stream>>>(src, dst, gCursor, bucketed, E, NB);
  s4_fill<<<NB, 256, 0, stream>>>(bucketed, bucketOff, rs, pdeg, ssrc, N);

  // weight prep + x -> bf16 (+ zero row)
  prep_w<<<(3 * 2 * 16384 + 255) / 256, 256, 0, stream>>>(W1, W2, wt);
  conv_bf16<<<(total64 + 255) / 256, 256, 0, stream>>>(x, hb, N * 64, total64);

  auto WT = [&](int layer, int mat) { return wt + ((size_t)(layer * 2 + mat)) * 2 * 16384; };

  // layer 0
  gather_zb<<<gGather, 256, 0, stream>>>(hb, rs, pdeg, ssrc, zb, N);
  mlp_mfma<<<gMlp, 256, 0, stream>>>(zb, WT(0, 0), WT(0, 1), b1, b2,
                                     nullptr, (unsigned short*)hb, N);
  // layer 1
  gather_zb<<<gGather, 256, 0, stream>>>(hb, rs, pdeg, ssrc, zb, N);
  mlp_mfma<<<gMlp, 256, 0, stream>>>(zb, WT(1, 0), WT(1, 1), b1 + DD, b2 + DD,
                                     nullptr, (unsigned short*)hb, N);
  // layer 2 -> f32 output
  gather_zb<<<gGather, 256, 0, stream>>>(hb, rs, pdeg, ssrc, zb, N);
  mlp_mfma<<<gMlp, 256, 0, stream>>>(zb, WT(2, 0), WT(2, 1), b1 + 2 * DD, b2 + 2 * DD,
                                     h_final, nullptr, N);

  classifier_k<<<(N * 16 + 255) / 256, 256, 0, stream>>>(h_final, Wc, bc, logits, N);
}

// Round 11
// 284.698 us; speedup vs baseline: 1.4054x; 1.0369x over previous
//
#include <hip/hip_runtime.h>

#define DD 128
#define CHUNK 6144   // edges per block in S1/S3
#define NBMAX 512    // max buckets (N <= 65536)
#define SCAP 8192    // per-bucket LDS staging capacity (padded len mean ~5100)
#define PADSLACK 2048  // max padding per bucket (128 nodes x 16)

typedef __attribute__((ext_vector_type(8))) short bf16x8;
typedef __attribute__((ext_vector_type(4))) float f32x4;

// ---------- bf16 helpers ----------
__device__ __forceinline__ unsigned bf16rne(float f) {
  unsigned u = __float_as_uint(f);
  return (u + 0x7FFFu + ((u >> 16) & 1u)) >> 16;
}
__device__ __forceinline__ unsigned packbf(float lo, float hi) {
  return bf16rne(lo) | (bf16rne(hi) << 16);
}
__device__ __forceinline__ float bflo(unsigned v) { return __uint_as_float(v << 16); }
__device__ __forceinline__ float bfhi(unsigned v) { return __uint_as_float(v & 0xFFFF0000u); }

// ---------- inclusive block scan over LDS array (256 threads, nb <= 512) ----------
__device__ void block_scan_incl(int* cnt, int* inc, int nb, int tid) {
  for (int i = tid; i < nb; i += 256) inc[i] = cnt[i];
  __syncthreads();
  for (int d = 1; d < nb; d <<= 1) {
    int i0 = tid, i1 = tid + 256;
    int v0 = 0, v1 = 0;
    if (i0 < nb && i0 >= d) v0 = inc[i0 - d];
    if (i1 < nb && i1 >= d) v1 = inc[i1 - d];
    __syncthreads();
    if (i0 < nb) inc[i0] += v0;
    if (i1 < nb) inc[i1] += v1;
    __syncthreads();
  }
}

// ---------- S1: bucket histogram (bucket = dst >> 7) ----------
__global__ __launch_bounds__(256) void s1_hist(const int* __restrict__ dst,
                                               int* __restrict__ bucketCount, int e) {
  __shared__ int h[NBMAX];
  int tid = threadIdx.x;
  for (int i = tid; i < NBMAX; i += 256) h[i] = 0;
  __syncthreads();
  int i0 = blockIdx.x * CHUNK;
  int i1 = min(i0 + CHUNK, e);
  for (int i = i0 + tid; i < i1; i += 256) atomicAdd(&h[dst[i] >> 7], 1);
  __syncthreads();
  for (int i = tid; i < NBMAX; i += 256)
    if (h[i]) atomicAdd(&bucketCount[i], h[i]);
}

// ---------- S2: scan bucket counts ----------
__global__ __launch_bounds__(256) void s2_scan(const int* __restrict__ bucketCount,
                                               int* __restrict__ bucketOff,
                                               int* __restrict__ gCursor,
                                               int* __restrict__ rs, int nb, int n, int e) {
  __shared__ int cnt[NBMAX], inc[NBMAX];
  int tid = threadIdx.x;
  for (int i = tid; i < nb; i += 256) cnt[i] = bucketCount[i];
  __syncthreads();
  block_scan_incl(cnt, inc, nb, tid);
  for (int i = tid; i < nb; i += 256) {
    int off = inc[i] - cnt[i];
    bucketOff[i] = off;
    gCursor[i] = off;
  }
  if (tid == 0) { bucketOff[nb] = e; rs[n] = e; }
}

// ---------- S3: block-local grouping + coalesced bucket scatter ----------
__global__ __launch_bounds__(256) void s3_scatter(const int* __restrict__ src,
                                                  const int* __restrict__ dst,
                                                  int* __restrict__ gCursor,
                                                  unsigned int* __restrict__ bucketed,
                                                  int e, int nb) {
  __shared__ int cnt[NBMAX], inc[NBMAX], base[NBMAX], cur[NBMAX];
  __shared__ unsigned int pairs[CHUNK];
  int tid = threadIdx.x;
  for (int i = tid; i < nb; i += 256) cnt[i] = 0;
  __syncthreads();
  int i0 = blockIdx.x * CHUNK;
  int i1 = min(i0 + CHUNK, e);
  for (int i = i0 + tid; i < i1; i += 256) atomicAdd(&cnt[dst[i] >> 7], 1);
  __syncthreads();
  block_scan_incl(cnt, inc, nb, tid);
  for (int b = tid; b < nb; b += 256) {
    int c = cnt[b];
    base[b] = c ? atomicAdd(&gCursor[b], c) : 0;
    cur[b] = inc[b] - c;
  }
  __syncthreads();
  for (int i = i0 + tid; i < i1; i += 256) {
    int d = dst[i];
    int p = atomicAdd(&cur[d >> 7], 1);
    pairs[p] = (unsigned)d | ((unsigned)src[i] << 16);
  }
  __syncthreads();
  int m = i1 - i0;
  for (int i = tid; i < m; i += 256) {
    unsigned w = pairs[i];
    int b = (int)(w & 0xFFFFu) >> 7;
    bucketed[base[b] + (i - (inc[b] - cnt[b]))] = w;
  }
}

// ---------- S4: per-bucket fill of PADDED ssrc; emits rs[] (padded start) + pdeg ----------
// Node segments padded to multiple of 16 (min 16) with index n (zero row).
__global__ __launch_bounds__(256) void s4_fill(const unsigned int* __restrict__ bucketed,
                                               const int* __restrict__ bucketOff,
                                               int* __restrict__ rs,
                                               unsigned short* __restrict__ pdeg,
                                               unsigned short* __restrict__ ssrc, int n) {
  __shared__ int cnt[128], pin[128], cur[128];
  __shared__ unsigned short outb[SCAP];
  int b = blockIdx.x;
  int bo = bucketOff[b], b1 = bucketOff[b + 1];
  int len = b1 - bo;
  int pstart = bo + b * PADSLACK;
  int tid = threadIdx.x;
  int n0 = b << 7;
  if (tid < 128) cnt[tid] = 0;
  __syncthreads();
  for (int i = tid; i < len; i += 256) atomicAdd(&cnt[bucketed[bo + i] & 127], 1);
  __syncthreads();
  int pc = 0;
  if (tid < 128) {
    pc = max(16, (cnt[tid] + 15) & ~15);
    pin[tid] = pc;
  }
  __syncthreads();
  for (int d = 1; d < 128; d <<= 1) {
    int v = 0;
    if (tid < 128 && tid >= d) v = pin[tid - d];
    __syncthreads();
    if (tid < 128) pin[tid] += v;
    __syncthreads();
  }
  int plen = pin[127];  // total padded length of this bucket
  if (tid < 128) {
    int off = pin[tid] - pc;
    cur[tid] = off;
    int node = n0 + tid;
    if (node < n) {
      rs[node] = pstart + off;
      pdeg[node] = (unsigned short)pc;
    }
  }
  __syncthreads();
  if (plen <= SCAP) {
    for (int i = tid; i < plen; i += 256) outb[i] = (unsigned short)n;
    __syncthreads();
    for (int i = tid; i < len; i += 256) {
      unsigned w = bucketed[bo + i];
      int p = atomicAdd(&cur[w & 127], 1);
      outb[p] = (unsigned short)(w >> 16);
    }
    __syncthreads();
    for (int i = tid; i < plen; i += 256) ssrc[pstart + i] = outb[i];  // coalesced
  } else {  // fallback (statistically unreachable)
    for (int i = tid; i < plen; i += 256) ssrc[pstart + i] = (unsigned short)n;
    __syncthreads();
    for (int i = tid; i < len; i += 256) {
      unsigned w = bucketed[bo + i];
      int p = atomicAdd(&cur[w & 127], 1);
      ssrc[pstart + p] = (unsigned short)(w >> 16);
    }
  }
}

// ---------- conv: f32 -> packed bf16x2, plus zero row at node N ----------
__global__ __launch_bounds__(256) void conv_bf16(const float* __restrict__ x,
                                                 unsigned int* __restrict__ hb,
                                                 int n64, int total64) {
  int i = blockIdx.x * 256 + threadIdx.x;
  if (i < n64) {
    float2 v = ((const float2*)x)[i];
    hb[i] = packbf(v.x, v.y);
  } else if (i < total64) {
    hb[i] = 0u;  // zero row read by padded gather slots
  }
}

// ---------- W prep: split W into (hi, lo) bf16, PRE-SWIZZLED [col][k] image ----------
__global__ __launch_bounds__(256) void prep_w(const float* __restrict__ W1,
                                              const float* __restrict__ W2,
                                              short* __restrict__ wt) {
  int idx = blockIdx.x * 256 + threadIdx.x;  // 3*2*16384
  if (idx >= 3 * 2 * 16384) return;
  int lm = idx >> 14;      // layer*2 + mat
  int e = idx & 16383;
  int k = e >> 7;
  int col = e & 127;
  int layer = lm >> 1, mat = lm & 1;
  const float* W = mat ? W2 : W1;
  float w = W[layer * 16384 + k * 128 + col];
  unsigned short h = (unsigned short)bf16rne(w);
  float hv = __uint_as_float((unsigned)h << 16);
  unsigned short lo = (unsigned short)bf16rne(w - hv);
  size_t base = (size_t)lm * 2 * 16384;
  int ksw = k ^ ((col & 7) << 3);  // swizzled k position
  wt[base + col * 128 + ksw] = (short)h;
  wt[base + 16384 + col * 128 + ksw] = (short)lo;
}

// ---------- aggregation: 1 node/wave, depth-16 pipeline, padded CSR ----------
// Segments are multiples of 16; pads point at zero row hb[n]. No per-edge clamp.
__global__ __launch_bounds__(256) void gather_zb(const unsigned int* __restrict__ hb,
                                                 const int* __restrict__ rs,
                                                 const unsigned short* __restrict__ pdeg,
                                                 const unsigned short* __restrict__ ssrc,
                                                 unsigned int* __restrict__ zb, int n) {
  int node = blockIdx.x * 4 + (threadIdx.x >> 6);
  if (node >= n) return;
  int lane = threadIdx.x & 63;
  int s0 = rs[node];
  int m = pdeg[node];
  unsigned v = hb[(unsigned)node * 64u + lane];
  float ax = bflo(v), ay = bfhi(v);
  unsigned A[16], B[16];
#pragma unroll
  for (int i = 0; i < 16; ++i)
    A[i] = hb[(unsigned)ssrc[s0 + i] * 64u + lane];
  int t1 = s0 + m;
  for (int t = s0 + 16; t < t1; t += 16) {
#pragma unroll
    for (int i = 0; i < 16; ++i)
      B[i] = hb[(unsigned)ssrc[t + i] * 64u + lane];
#pragma unroll
    for (int i = 0; i < 16; ++i) {
      ax += bflo(A[i]);
      ay += bfhi(A[i]);
    }
#pragma unroll
    for (int i = 0; i < 16; ++i) A[i] = B[i];
  }
#pragma unroll
  for (int i = 0; i < 16; ++i) {
    ax += bflo(A[i]);
    ay += bfhi(A[i]);
  }
  zb[(unsigned)node * 64u + lane] = packbf(ax, ay);
}

// ---------- MFMA MLP: hout = relu(z@W1+b1)@W2+b2; optional fused classifier ----------
// 256 threads = 4 waves in 2x2: wave w -> rows (w&1)*64..+64, cols (w>>1)*64..+64.
__global__ __launch_bounds__(256, 2) void mlp_mfma(
    const unsigned int* __restrict__ zb,
    const short* __restrict__ Wt1, const short* __restrict__ Wt2,
    const float* __restrict__ b1, const float* __restrict__ b2,
    float* __restrict__ fout, unsigned short* __restrict__ hbout,
    const float* __restrict__ Wc, const float* __restrict__ bc,
    float* __restrict__ lout, int n) {
  __shared__ char wbuf[32768];      // one weight part (swizzled image); Wc in tail phase
  __shared__ char hsb[128 * 256];   // 32KB swizzled bf16 h-tile
  int tid = threadIdx.x;
  int w = tid >> 6, lane = tid & 63;
  int lr = lane & 15, hi = lane >> 4;
  int wr = (w & 1) * 64;
  int wc = (w >> 1) * 64;
  int node0 = blockIdx.x * 128;

  bf16x8 a[4][4];
#pragma unroll
  for (int t = 0; t < 4; ++t) {
    int row = node0 + wr + t * 16 + lr;
    row = min(row, n - 1);
    const char* rp = (const char*)(zb + (size_t)row * 64);
#pragma unroll
    for (int ks = 0; ks < 4; ++ks)
      a[t][ks] = *(const bf16x8*)(rp + ks * 64 + hi * 16);
  }

  f32x4 acc[4][4];
#pragma unroll
  for (int ct = 0; ct < 4; ++ct) {
    float bb = b1[wc + ct * 16 + lr];
#pragma unroll
    for (int t = 0; t < 4; ++t) acc[t][ct] = (f32x4){bb, bb, bb, bb};
  }

#pragma unroll
  for (int p = 0; p < 2; ++p) {
    __syncthreads();
    {
      const char* gs = (const char*)(Wt1 + p * 16384);
      for (int i = tid * 16; i < 32768; i += 256 * 16)
        *(float4*)&wbuf[i] = *(const float4*)(gs + i);
    }
    __syncthreads();
#pragma unroll
    for (int ct = 0; ct < 4; ++ct) {
      int col = wc + ct * 16 + lr;
      int cx = (col & 7) << 4;
#pragma unroll
      for (int ks = 0; ks < 4; ++ks) {
        bf16x8 b = *(const bf16x8*)&wbuf[(col * 256 + ks * 64 + hi * 16) ^ cx];
#pragma unroll
        for (int t = 0; t < 4; ++t)
          acc[t][ct] = __builtin_amdgcn_mfma_f32_16x16x32_bf16(a[t][ks], b, acc[t][ct], 0, 0, 0);
      }
    }
  }

#pragma unroll
  for (int t = 0; t < 4; ++t)
#pragma unroll
    for (int ct = 0; ct < 4; ++ct)
#pragma unroll
      for (int r = 0; r < 4; ++r) {
        int row = wr + t * 16 + hi * 4 + r;
        int col = wc + ct * 16 + lr;
        float v = fmaxf(acc[t][ct][r], 0.f);
        int byte = (row * 256 + col * 2) ^ ((row & 7) << 4);
        *(unsigned short*)&hsb[byte] = (unsigned short)bf16rne(v);
      }
  __syncthreads();

  bf16x8 a2[4][4];
#pragma unroll
  for (int t = 0; t < 4; ++t) {
    int row = wr + t * 16 + lr;
    int xr = (row & 7) << 4;
#pragma unroll
    for (int ks = 0; ks < 4; ++ks)
      a2[t][ks] = *(const bf16x8*)&hsb[(row * 256 + ks * 64 + hi * 16) ^ xr];
  }

#pragma unroll
  for (int ct = 0; ct < 4; ++ct) {
    float bb = b2[wc + ct * 16 + lr];
#pragma unroll
    for (int t = 0; t < 4; ++t) acc[t][ct] = (f32x4){bb, bb, bb, bb};
  }

#pragma unroll
  for (int p = 0; p < 2; ++p) {
    __syncthreads();
    {
      const char* gs = (const char*)(Wt2 + p * 16384);
      for (int i = tid * 16; i < 32768; i += 256 * 16)
        *(float4*)&wbuf[i] = *(const float4*)(gs + i);
    }
    __syncthreads();
#pragma unroll
    for (int ct = 0; ct < 4; ++ct) {
      int col = wc + ct * 16 + lr;
      int cx = (col & 7) << 4;
#pragma unroll
      for (int ks = 0; ks < 4; ++ks) {
        bf16x8 b = *(const bf16x8*)&wbuf[(col * 256 + ks * 64 + hi * 16) ^ cx];
#pragma unroll
        for (int t = 0; t < 4; ++t)
          acc[t][ct] = __builtin_amdgcn_mfma_f32_16x16x32_bf16(a2[t][ks], b, acc[t][ct], 0, 0, 0);
      }
    }
  }

#pragma unroll
  for (int t = 0; t < 4; ++t)
#pragma unroll
    for (int ct = 0; ct < 4; ++ct)
#pragma unroll
      for (int r = 0; r < 4; ++r) {
        int node = node0 + wr + t * 16 + hi * 4 + r;
        if (node < n) {
          int col = wc + ct * 16 + lr;
          float v = acc[t][ct][r];
          if (fout) fout[(size_t)node * DD + col] = v;
          if (hbout) hbout[(size_t)node * DD + col] = (unsigned short)bf16rne(v);
        }
      }

  // ---- fused classifier tail (layer 2 only): logits = h @ Wc + bc ----
  if (lout) {
    __syncthreads();  // all wbuf/hsb reads done
    // stage Wc into wbuf (f32, 8KB) and final h (bf16) into swizzled hsb
    float* wcb = (float*)wbuf;
    for (int i = tid; i < DD * 16; i += 256) wcb[i] = Wc[i];
#pragma unroll
    for (int t = 0; t < 4; ++t)
#pragma unroll
      for (int ct = 0; ct < 4; ++ct)
#pragma unroll
        for (int r = 0; r < 4; ++r) {
          int row = wr + t * 16 + hi * 4 + r;
          int col = wc + ct * 16 + lr;
          int byte = (row * 256 + col * 2) ^ ((row & 7) << 4);
          *(unsigned short*)&hsb[byte] = (unsigned short)bf16rne(acc[t][ct][r]);
        }
    __syncthreads();
    int node = tid >> 1;           // 0..127
    int lbase = (tid & 1) * 8;     // labels 0-7 or 8-15
    float lacc[8];
#pragma unroll
    for (int j = 0; j < 8; ++j) lacc[j] = bc[lbase + j];
    int xr = (node & 7) << 4;
    for (int c = 0; c < DD; ++c) {
      unsigned short hv16 = *(const unsigned short*)&hsb[(node * 256 + c * 2) ^ xr];
      float hv = __uint_as_float((unsigned)hv16 << 16);
      const float* wrow = &wcb[c * 16 + lbase];
#pragma unroll
      for (int j = 0; j < 8; ++j) lacc[j] += hv * wrow[j];
    }
    int gn = node0 + node;
    if (gn < n) {
#pragma unroll
      for (int j = 0; j < 8; ++j) lout[(size_t)gn * 16 + lbase + j] = lacc[j];
    }
  }
}

extern "C" void kernel_launch(void* const* d_in, const int* in_sizes, int n_in,
                              void* d_out, int out_size, void* d_ws, size_t ws_size,
                              hipStream_t stream) {
  const float* x = (const float*)d_in[0];
  const int* ei = (const int*)d_in[1];
  const float* W1 = (const float*)d_in[2];
  const float* b1 = (const float*)d_in[3];
  const float* W2 = (const float*)d_in[4];
  const float* b2 = (const float*)d_in[5];
  const float* Wc = (const float*)d_in[6];
  const float* bc = (const float*)d_in[7];

  const int N = in_sizes[0] / DD;
  const int E = in_sizes[1] / 2;
  const int* src = ei;
  const int* dst = ei + E;
  const int NB = (N + 127) >> 7;

  float* outp = (float*)d_out;
  float* h_final = outp;
  float* logits = outp + (size_t)N * DD;

  char* ws = (char*)d_ws;
  size_t off = 0;
  auto alloc = [&](size_t bytes) {
    char* p = ws + off;
    off = (off + bytes + 255) & ~(size_t)255;
    return p;
  };
  unsigned int* zb = (unsigned int*)alloc((size_t)N * 64 * 4);        // packed bf16 z
  unsigned int* hb = (unsigned int*)alloc((size_t)(N + 1) * 64 * 4);  // packed bf16 h + zero row
  short* wt = (short*)alloc((size_t)3 * 2 * 2 * 16384 * 2);           // split swizzled W
  int* bucketCount = (int*)alloc(NBMAX * 4);
  int* bucketOff = (int*)alloc((NBMAX + 1) * 4);
  int* gCursor = (int*)alloc(NBMAX * 4);
  int* rs = (int*)alloc((size_t)(N + 1) * 4);
  unsigned short* pdeg = (unsigned short*)alloc((size_t)N * 2);
  unsigned int* bucketed = (unsigned int*)alloc((size_t)E * 4);
  unsigned short* ssrc = (unsigned short*)alloc(((size_t)E + (size_t)NB * PADSLACK) * 2);

  const int gEdge = (E + CHUNK - 1) / CHUNK;
  const int gGather = (N + 3) / 4;  // 4 nodes/block, 1 per wave
  const int gMlp = (N + 127) / 128;
  const int total64 = (N + 1) * 64;

  // CSR build (padded)
  hipMemsetAsync(bucketCount, 0, NBMAX * 4, stream);
  s1_hist<<<gEdge, 256, 0, stream>>>(dst, bucketCount, E);
  s2_scan<<<1, 256, 0, stream>>>(bucketCount, bucketOff, gCursor, rs, NB, N, E);
  s3_scatter<<<gEdge, 256, 0, stream>>>(src, dst, gCursor, bucketed, E, NB);
  s4_fill<<<NB, 256, 0, stream>>>(bucketed, bucketOff, rs, pdeg, ssrc, N);

  // weight prep + x -> bf16 (+ zero row)
  prep_w<<<(3 * 2 * 16384 + 255) / 256, 256, 0, stream>>>(W1, W2, wt);
  conv_bf16<<<(total64 + 255) / 256, 256, 0, stream>>>(x, hb, N * 64, total64);

  auto WT = [&](int layer, int mat) { return wt + ((size_t)(layer * 2 + mat)) * 2 * 16384; };

  // layer 0
  gather_zb<<<gGather, 256, 0, stream>>>(hb, rs, pdeg, ssrc, zb, N);
  mlp_mfma<<<gMlp, 256, 0, stream>>>(zb, WT(0, 0), WT(0, 1), b1, b2,
                                     nullptr, (unsigned short*)hb, nullptr, nullptr, nullptr, N);
  // layer 1
  gather_zb<<<gGather, 256, 0, stream>>>(hb, rs, pdeg, ssrc, zb, N);
  mlp_mfma<<<gMlp, 256, 0, stream>>>(zb, WT(1, 0), WT(1, 1), b1 + DD, b2 + DD,
                                     nullptr, (unsigned short*)hb, nullptr, nullptr, nullptr, N);
  // layer 2 -> f32 h + fused classifier -> logits
  gather_zb<<<gGather, 256, 0, stream>>>(hb, rs, pdeg, ssrc, zb, N);
  mlp_mfma<<<gMlp, 256, 0, stream>>>(zb, WT(2, 0), WT(2, 1), b1 + 2 * DD, b2 + 2 * DD,
                                     h_final, nullptr, Wc, bc, logits, N);
}

// Round 12
// 273.942 us; speedup vs baseline: 1.4606x; 1.0393x over previous
//
#include <hip/hip_runtime.h>

#define DD 128
#define CHUNK 6144   // edges per block in S1/S3
#define NBMAX 512    // max buckets (N <= 65536)
#define SCAP 8192    // per-bucket LDS staging capacity (padded len mean ~5100)
#define PADSLACK 2048  // max padding per bucket (128 nodes x 16)

typedef __attribute__((ext_vector_type(8))) short bf16x8;
typedef __attribute__((ext_vector_type(4))) float f32x4;

// ---------- bf16 helpers ----------
__device__ __forceinline__ unsigned bf16rne(float f) {
  unsigned u = __float_as_uint(f);
  return (u + 0x7FFFu + ((u >> 16) & 1u)) >> 16;
}
__device__ __forceinline__ unsigned packbf(float lo, float hi) {
  return bf16rne(lo) | (bf16rne(hi) << 16);
}
__device__ __forceinline__ float bflo(unsigned v) { return __uint_as_float(v << 16); }
__device__ __forceinline__ float bfhi(unsigned v) { return __uint_as_float(v & 0xFFFF0000u); }

// ---------- inclusive block scan over LDS array (256 threads, nb <= 512) ----------
__device__ void block_scan_incl(int* cnt, int* inc, int nb, int tid) {
  for (int i = tid; i < nb; i += 256) inc[i] = cnt[i];
  __syncthreads();
  for (int d = 1; d < nb; d <<= 1) {
    int i0 = tid, i1 = tid + 256;
    int v0 = 0, v1 = 0;
    if (i0 < nb && i0 >= d) v0 = inc[i0 - d];
    if (i1 < nb && i1 >= d) v1 = inc[i1 - d];
    __syncthreads();
    if (i0 < nb) inc[i0] += v0;
    if (i1 < nb) inc[i1] += v1;
    __syncthreads();
  }
}

// ---------- S1: bucket histogram (bucket = dst >> 7) ----------
__global__ __launch_bounds__(256) void s1_hist(const int* __restrict__ dst,
                                               int* __restrict__ bucketCount, int e) {
  __shared__ int h[NBMAX];
  int tid = threadIdx.x;
  for (int i = tid; i < NBMAX; i += 256) h[i] = 0;
  __syncthreads();
  int i0 = blockIdx.x * CHUNK;
  int i1 = min(i0 + CHUNK, e);
  for (int i = i0 + tid; i < i1; i += 256) atomicAdd(&h[dst[i] >> 7], 1);
  __syncthreads();
  for (int i = tid; i < NBMAX; i += 256)
    if (h[i]) atomicAdd(&bucketCount[i], h[i]);
}

// ---------- S2: scan bucket counts ----------
__global__ __launch_bounds__(256) void s2_scan(const int* __restrict__ bucketCount,
                                               int* __restrict__ bucketOff,
                                               int* __restrict__ gCursor,
                                               int* __restrict__ rs, int nb, int n, int e) {
  __shared__ int cnt[NBMAX], inc[NBMAX];
  int tid = threadIdx.x;
  for (int i = tid; i < nb; i += 256) cnt[i] = bucketCount[i];
  __syncthreads();
  block_scan_incl(cnt, inc, nb, tid);
  for (int i = tid; i < nb; i += 256) {
    int off = inc[i] - cnt[i];
    bucketOff[i] = off;
    gCursor[i] = off;
  }
  if (tid == 0) { bucketOff[nb] = e; rs[n] = e; }
}

// ---------- S3: block-local grouping + coalesced bucket scatter ----------
__global__ __launch_bounds__(256) void s3_scatter(const int* __restrict__ src,
                                                  const int* __restrict__ dst,
                                                  int* __restrict__ gCursor,
                                                  unsigned int* __restrict__ bucketed,
                                                  int e, int nb) {
  __shared__ int cnt[NBMAX], inc[NBMAX], base[NBMAX], cur[NBMAX];
  __shared__ unsigned int pairs[CHUNK];
  int tid = threadIdx.x;
  for (int i = tid; i < nb; i += 256) cnt[i] = 0;
  __syncthreads();
  int i0 = blockIdx.x * CHUNK;
  int i1 = min(i0 + CHUNK, e);
  for (int i = i0 + tid; i < i1; i += 256) atomicAdd(&cnt[dst[i] >> 7], 1);
  __syncthreads();
  block_scan_incl(cnt, inc, nb, tid);
  for (int b = tid; b < nb; b += 256) {
    int c = cnt[b];
    base[b] = c ? atomicAdd(&gCursor[b], c) : 0;
    cur[b] = inc[b] - c;
  }
  __syncthreads();
  for (int i = i0 + tid; i < i1; i += 256) {
    int d = dst[i];
    int p = atomicAdd(&cur[d >> 7], 1);
    pairs[p] = (unsigned)d | ((unsigned)src[i] << 16);
  }
  __syncthreads();
  int m = i1 - i0;
  for (int i = tid; i < m; i += 256) {
    unsigned w = pairs[i];
    int b = (int)(w & 0xFFFFu) >> 7;
    bucketed[base[b] + (i - (inc[b] - cnt[b]))] = w;
  }
}

// ---------- S4: per-bucket fill of PADDED ssrc; emits rs[] (padded start) + pdeg ----------
// Node segments padded to multiple of 16 (min 16) with index n (zero row).
__global__ __launch_bounds__(256) void s4_fill(const unsigned int* __restrict__ bucketed,
                                               const int* __restrict__ bucketOff,
                                               int* __restrict__ rs,
                                               unsigned short* __restrict__ pdeg,
                                               unsigned short* __restrict__ ssrc, int n) {
  __shared__ int cnt[128], pin[128], cur[128];
  __shared__ unsigned short outb[SCAP];
  int b = blockIdx.x;
  int bo = bucketOff[b], b1 = bucketOff[b + 1];
  int len = b1 - bo;
  int pstart = bo + b * PADSLACK;
  int tid = threadIdx.x;
  int n0 = b << 7;
  if (tid < 128) cnt[tid] = 0;
  __syncthreads();
  for (int i = tid; i < len; i += 256) atomicAdd(&cnt[bucketed[bo + i] & 127], 1);
  __syncthreads();
  int pc = 0;
  if (tid < 128) {
    pc = max(16, (cnt[tid] + 15) & ~15);
    pin[tid] = pc;
  }
  __syncthreads();
  for (int d = 1; d < 128; d <<= 1) {
    int v = 0;
    if (tid < 128 && tid >= d) v = pin[tid - d];
    __syncthreads();
    if (tid < 128) pin[tid] += v;
    __syncthreads();
  }
  int plen = pin[127];  // total padded length of this bucket
  if (tid < 128) {
    int off = pin[tid] - pc;
    cur[tid] = off;
    int node = n0 + tid;
    if (node < n) {
      rs[node] = pstart + off;
      pdeg[node] = (unsigned short)pc;
    }
  }
  __syncthreads();
  if (plen <= SCAP) {
    for (int i = tid; i < plen; i += 256) outb[i] = (unsigned short)n;
    __syncthreads();
    for (int i = tid; i < len; i += 256) {
      unsigned w = bucketed[bo + i];
      int p = atomicAdd(&cur[w & 127], 1);
      outb[p] = (unsigned short)(w >> 16);
    }
    __syncthreads();
    for (int i = tid; i < plen; i += 256) ssrc[pstart + i] = outb[i];  // coalesced
  } else {  // fallback (statistically unreachable)
    for (int i = tid; i < plen; i += 256) ssrc[pstart + i] = (unsigned short)n;
    __syncthreads();
    for (int i = tid; i < len; i += 256) {
      unsigned w = bucketed[bo + i];
      int p = atomicAdd(&cur[w & 127], 1);
      ssrc[pstart + p] = (unsigned short)(w >> 16);
    }
  }
}

// ---------- conv: f32 -> packed bf16x2, plus zero row at node N ----------
__global__ __launch_bounds__(256) void conv_bf16(const float* __restrict__ x,
                                                 unsigned int* __restrict__ hb,
                                                 int n64, int total64) {
  int i = blockIdx.x * 256 + threadIdx.x;
  if (i < n64) {
    float2 v = ((const float2*)x)[i];
    hb[i] = packbf(v.x, v.y);
  } else if (i < total64) {
    hb[i] = 0u;  // zero row read by padded gather slots
  }
}

// ---------- W prep: bf16 weights, PRE-SWIZZLED [col][k] image (hi part only) ----------
__global__ __launch_bounds__(256) void prep_w(const float* __restrict__ W1,
                                              const float* __restrict__ W2,
                                              short* __restrict__ wt) {
  int idx = blockIdx.x * 256 + threadIdx.x;  // 3*2*16384
  if (idx >= 3 * 2 * 16384) return;
  int lm = idx >> 14;      // layer*2 + mat
  int e = idx & 16383;
  int k = e >> 7;
  int col = e & 127;
  int layer = lm >> 1, mat = lm & 1;
  const float* W = mat ? W2 : W1;
  float w = W[layer * 16384 + k * 128 + col];
  unsigned short h = (unsigned short)bf16rne(w);
  int ksw = k ^ ((col & 7) << 3);  // swizzled k position
  wt[(size_t)lm * 16384 + col * 128 + ksw] = (short)h;
}

// ---------- aggregation: 1 node/wave, depth-16 pipeline, padded CSR ----------
// Segments are multiples of 16; pads point at zero row hb[n]. No per-edge clamp.
__global__ __launch_bounds__(256) void gather_zb(const unsigned int* __restrict__ hb,
                                                 const int* __restrict__ rs,
                                                 const unsigned short* __restrict__ pdeg,
                                                 const unsigned short* __restrict__ ssrc,
                                                 unsigned int* __restrict__ zb, int n) {
  int node = blockIdx.x * 4 + (threadIdx.x >> 6);
  if (node >= n) return;
  int lane = threadIdx.x & 63;
  int s0 = rs[node];
  int m = pdeg[node];
  unsigned v = hb[(unsigned)node * 64u + lane];
  float ax = bflo(v), ay = bfhi(v);
  unsigned A[16], B[16];
#pragma unroll
  for (int i = 0; i < 16; ++i)
    A[i] = hb[(unsigned)ssrc[s0 + i] * 64u + lane];
  int t1 = s0 + m;
  for (int t = s0 + 16; t < t1; t += 16) {
#pragma unroll
    for (int i = 0; i < 16; ++i)
      B[i] = hb[(unsigned)ssrc[t + i] * 64u + lane];
#pragma unroll
    for (int i = 0; i < 16; ++i) {
      ax += bflo(A[i]);
      ay += bfhi(A[i]);
    }
#pragma unroll
    for (int i = 0; i < 16; ++i) A[i] = B[i];
  }
#pragma unroll
  for (int i = 0; i < 16; ++i) {
    ax += bflo(A[i]);
    ay += bfhi(A[i]);
  }
  zb[(unsigned)node * 64u + lane] = packbf(ax, ay);
}

// ---------- MFMA MLP: hout = relu(z@W1+b1)@W2+b2; optional fused classifier ----------
// 256 threads = 4 waves in 2x2: wave w -> rows (w&1)*64..+64, cols (w>>1)*64..+64.
// Single bf16 weight image per matmul (32KB), staged once; 64 MFMA/wave/matmul.
__global__ __launch_bounds__(256, 2) void mlp_mfma(
    const unsigned int* __restrict__ zb,
    const short* __restrict__ Wt1, const short* __restrict__ Wt2,
    const float* __restrict__ b1, const float* __restrict__ b2,
    float* __restrict__ fout, unsigned short* __restrict__ hbout,
    const float* __restrict__ Wc, const float* __restrict__ bc,
    float* __restrict__ lout, int n) {
  __shared__ char wbuf[32768];      // full weight matrix (swizzled image); Wc in tail phase
  __shared__ char hsb[128 * 256];   // 32KB swizzled bf16 h-tile
  int tid = threadIdx.x;
  int w = tid >> 6, lane = tid & 63;
  int lr = lane & 15, hi = lane >> 4;
  int wr = (w & 1) * 64;
  int wc = (w >> 1) * 64;
  int node0 = blockIdx.x * 128;

  bf16x8 a[4][4];
#pragma unroll
  for (int t = 0; t < 4; ++t) {
    int row = node0 + wr + t * 16 + lr;
    row = min(row, n - 1);
    const char* rp = (const char*)(zb + (size_t)row * 64);
#pragma unroll
    for (int ks = 0; ks < 4; ++ks)
      a[t][ks] = *(const bf16x8*)(rp + ks * 64 + hi * 16);
  }

  f32x4 acc[4][4];
#pragma unroll
  for (int ct = 0; ct < 4; ++ct) {
    float bb = b1[wc + ct * 16 + lr];
#pragma unroll
    for (int t = 0; t < 4; ++t) acc[t][ct] = (f32x4){bb, bb, bb, bb};
  }

  // matmul1: z @ W1 (single bf16 part)
  {
    const char* gs = (const char*)Wt1;
    for (int i = tid * 16; i < 32768; i += 256 * 16)
      *(float4*)&wbuf[i] = *(const float4*)(gs + i);
  }
  __syncthreads();
#pragma unroll
  for (int ct = 0; ct < 4; ++ct) {
    int col = wc + ct * 16 + lr;
    int cx = (col & 7) << 4;
#pragma unroll
    for (int ks = 0; ks < 4; ++ks) {
      bf16x8 b = *(const bf16x8*)&wbuf[(col * 256 + ks * 64 + hi * 16) ^ cx];
#pragma unroll
      for (int t = 0; t < 4; ++t)
        acc[t][ct] = __builtin_amdgcn_mfma_f32_16x16x32_bf16(a[t][ks], b, acc[t][ct], 0, 0, 0);
    }
  }

  // relu -> swizzled LDS bf16 (C layout: row=(lane>>4)*4+r, col=lane&15)
#pragma unroll
  for (int t = 0; t < 4; ++t)
#pragma unroll
    for (int ct = 0; ct < 4; ++ct)
#pragma unroll
      for (int r = 0; r < 4; ++r) {
        int row = wr + t * 16 + hi * 4 + r;
        int col = wc + ct * 16 + lr;
        float v = fmaxf(acc[t][ct][r], 0.f);
        int byte = (row * 256 + col * 2) ^ ((row & 7) << 4);
        *(unsigned short*)&hsb[byte] = (unsigned short)bf16rne(v);
      }
  __syncthreads();

  bf16x8 a2[4][4];
#pragma unroll
  for (int t = 0; t < 4; ++t) {
    int row = wr + t * 16 + lr;
    int xr = (row & 7) << 4;
#pragma unroll
    for (int ks = 0; ks < 4; ++ks)
      a2[t][ks] = *(const bf16x8*)&hsb[(row * 256 + ks * 64 + hi * 16) ^ xr];
  }

#pragma unroll
  for (int ct = 0; ct < 4; ++ct) {
    float bb = b2[wc + ct * 16 + lr];
#pragma unroll
    for (int t = 0; t < 4; ++t) acc[t][ct] = (f32x4){bb, bb, bb, bb};
  }

  // matmul2: h @ W2 (single bf16 part); reuse wbuf after all matmul1 reads done
  __syncthreads();
  {
    const char* gs = (const char*)Wt2;
    for (int i = tid * 16; i < 32768; i += 256 * 16)
      *(float4*)&wbuf[i] = *(const float4*)(gs + i);
  }
  __syncthreads();
#pragma unroll
  for (int ct = 0; ct < 4; ++ct) {
    int col = wc + ct * 16 + lr;
    int cx = (col & 7) << 4;
#pragma unroll
    for (int ks = 0; ks < 4; ++ks) {
      bf16x8 b = *(const bf16x8*)&wbuf[(col * 256 + ks * 64 + hi * 16) ^ cx];
#pragma unroll
      for (int t = 0; t < 4; ++t)
        acc[t][ct] = __builtin_amdgcn_mfma_f32_16x16x32_bf16(a2[t][ks], b, acc[t][ct], 0, 0, 0);
    }
  }

#pragma unroll
  for (int t = 0; t < 4; ++t)
#pragma unroll
    for (int ct = 0; ct < 4; ++ct)
#pragma unroll
      for (int r = 0; r < 4; ++r) {
        int node = node0 + wr + t * 16 + hi * 4 + r;
        if (node < n) {
          int col = wc + ct * 16 + lr;
          float v = acc[t][ct][r];
          if (fout) fout[(size_t)node * DD + col] = v;
          if (hbout) hbout[(size_t)node * DD + col] = (unsigned short)bf16rne(v);
        }
      }

  // ---- fused classifier tail (layer 2 only): logits = h @ Wc + bc ----
  if (lout) {
    __syncthreads();  // all wbuf/hsb reads done
    float* wcb = (float*)wbuf;
    for (int i = tid; i < DD * 16; i += 256) wcb[i] = Wc[i];
#pragma unroll
    for (int t = 0; t < 4; ++t)
#pragma unroll
      for (int ct = 0; ct < 4; ++ct)
#pragma unroll
        for (int r = 0; r < 4; ++r) {
          int row = wr + t * 16 + hi * 4 + r;
          int col = wc + ct * 16 + lr;
          int byte = (row * 256 + col * 2) ^ ((row & 7) << 4);
          *(unsigned short*)&hsb[byte] = (unsigned short)bf16rne(acc[t][ct][r]);
        }
    __syncthreads();
    int node = tid >> 1;           // 0..127
    int lbase = (tid & 1) * 8;     // labels 0-7 or 8-15
    float lacc[8];
#pragma unroll
    for (int j = 0; j < 8; ++j) lacc[j] = bc[lbase + j];
    int xr = (node & 7) << 4;
    for (int c = 0; c < DD; ++c) {
      unsigned short hv16 = *(const unsigned short*)&hsb[(node * 256 + c * 2) ^ xr];
      float hv = __uint_as_float((unsigned)hv16 << 16);
      const float* wrow = &wcb[c * 16 + lbase];
#pragma unroll
      for (int j = 0; j < 8; ++j) lacc[j] += hv * wrow[j];
    }
    int gn = node0 + node;
    if (gn < n) {
#pragma unroll
      for (int j = 0; j < 8; ++j) lout[(size_t)gn * 16 + lbase + j] = lacc[j];
    }
  }
}

extern "C" void kernel_launch(void* const* d_in, const int* in_sizes, int n_in,
                              void* d_out, int out_size, void* d_ws, size_t ws_size,
                              hipStream_t stream) {
  const float* x = (const float*)d_in[0];
  const int* ei = (const int*)d_in[1];
  const float* W1 = (const float*)d_in[2];
  const float* b1 = (const float*)d_in[3];
  const float* W2 = (const float*)d_in[4];
  const float* b2 = (const float*)d_in[5];
  const float* Wc = (const float*)d_in[6];
  const float* bc = (const float*)d_in[7];

  const int N = in_sizes[0] / DD;
  const int E = in_sizes[1] / 2;
  const int* src = ei;
  const int* dst = ei + E;
  const int NB = (N + 127) >> 7;

  float* outp = (float*)d_out;
  float* h_final = outp;
  float* logits = outp + (size_t)N * DD;

  char* ws = (char*)d_ws;
  size_t off = 0;
  auto alloc = [&](size_t bytes) {
    char* p = ws + off;
    off = (off + bytes + 255) & ~(size_t)255;
    return p;
  };
  unsigned int* zb = (unsigned int*)alloc((size_t)N * 64 * 4);        // packed bf16 z
  unsigned int* hb = (unsigned int*)alloc((size_t)(N + 1) * 64 * 4);  // packed bf16 h + zero row
  short* wt = (short*)alloc((size_t)3 * 2 * 16384 * 2);               // bf16 swizzled W (hi only)
  int* bucketCount = (int*)alloc(NBMAX * 4);
  int* bucketOff = (int*)alloc((NBMAX + 1) * 4);
  int* gCursor = (int*)alloc(NBMAX * 4);
  int* rs = (int*)alloc((size_t)(N + 1) * 4);
  unsigned short* pdeg = (unsigned short*)alloc((size_t)N * 2);
  unsigned int* bucketed = (unsigned int*)alloc((size_t)E * 4);
  unsigned short* ssrc = (unsigned short*)alloc(((size_t)E + (size_t)NB * PADSLACK) * 2);

  const int gEdge = (E + CHUNK - 1) / CHUNK;
  const int gGather = (N + 3) / 4;  // 4 nodes/block, 1 per wave
  const int gMlp = (N + 127) / 128;
  const int total64 = (N + 1) * 64;

  // CSR build (padded)
  hipMemsetAsync(bucketCount, 0, NBMAX * 4, stream);
  s1_hist<<<gEdge, 256, 0, stream>>>(dst, bucketCount, E);
  s2_scan<<<1, 256, 0, stream>>>(bucketCount, bucketOff, gCursor, rs, NB, N, E);
  s3_scatter<<<gEdge, 256, 0, stream>>>(src, dst, gCursor, bucketed, E, NB);
  s4_fill<<<NB, 256, 0, stream>>>(bucketed, bucketOff, rs, pdeg, ssrc, N);

  // weight prep + x -> bf16 (+ zero row)
  prep_w<<<(3 * 2 * 16384 + 255) / 256, 256, 0, stream>>>(W1, W2, wt);
  conv_bf16<<<(total64 + 255) / 256, 256, 0, stream>>>(x, hb, N * 64, total64);

  auto WT = [&](int layer, int mat) { return wt + ((size_t)(layer * 2 + mat)) * 16384; };

  // layer 0
  gather_zb<<<gGather, 256, 0, stream>>>(hb, rs, pdeg, ssrc, zb, N);
  mlp_mfma<<<gMlp, 256, 0, stream>>>(zb, WT(0, 0), WT(0, 1), b1, b2,
                                     nullptr, (unsigned short*)hb, nullptr, nullptr, nullptr, N);
  // layer 1
  gather_zb<<<gGather, 256, 0, stream>>>(hb, rs, pdeg, ssrc, zb, N);
  mlp_mfma<<<gMlp, 256, 0, stream>>>(zb, WT(1, 0), WT(1, 1), b1 + DD, b2 + DD,
                                     nullptr, (unsigned short*)hb, nullptr, nullptr, nullptr, N);
  // layer 2 -> f32 h + fused classifier -> logits
  gather_zb<<<gGather, 256, 0, stream>>>(hb, rs, pdeg, ssrc, zb, N);
  mlp_mfma<<<gMlp, 256, 0, stream>>>(zb, WT(2, 0), WT(2, 1), b1 + 2 * DD, b2 + 2 * DD,
                                     h_final, nullptr, Wc, bc, logits, N);
}

// Round 13
// 263.048 us; speedup vs baseline: 1.5211x; 1.0414x over previous
//
#include <hip/hip_runtime.h>

#define DD 128
#define CHUNK 6144    // edges per block in S1/S3
#define NBMAX 512     // max buckets (N <= 65536)
#define SCAP 8192     // per-bucket LDS staging capacity
#define PADSLACK 1024 // max padding per bucket (128 nodes x 8)

typedef __attribute__((ext_vector_type(8))) short bf16x8;
typedef __attribute__((ext_vector_type(4))) float f32x4;

// ---------- bf16 helpers ----------
__device__ __forceinline__ unsigned bf16rne(float f) {
  unsigned u = __float_as_uint(f);
  return (u + 0x7FFFu + ((u >> 16) & 1u)) >> 16;
}
__device__ __forceinline__ unsigned packbf(float lo, float hi) {
  return bf16rne(lo) | (bf16rne(hi) << 16);
}
__device__ __forceinline__ float bflo(unsigned v) { return __uint_as_float(v << 16); }
__device__ __forceinline__ float bfhi(unsigned v) { return __uint_as_float(v & 0xFFFF0000u); }

// ---------- inclusive block scan over LDS array (256 threads, nb <= 512) ----------
__device__ void block_scan_incl(int* cnt, int* inc, int nb, int tid) {
  for (int i = tid; i < nb; i += 256) inc[i] = cnt[i];
  __syncthreads();
  for (int d = 1; d < nb; d <<= 1) {
    int i0 = tid, i1 = tid + 256;
    int v0 = 0, v1 = 0;
    if (i0 < nb && i0 >= d) v0 = inc[i0 - d];
    if (i1 < nb && i1 >= d) v1 = inc[i1 - d];
    __syncthreads();
    if (i0 < nb) inc[i0] += v0;
    if (i1 < nb) inc[i1] += v1;
    __syncthreads();
  }
}

// ---------- fat setup kernel: [s1 hist | conv bf16 | prep W+Wc] by block range ----------
__global__ __launch_bounds__(256) void setup_fat(
    const int* __restrict__ dst, int* __restrict__ bucketCount, int e,
    const float* __restrict__ x, unsigned int* __restrict__ hb, int n64, int total64,
    const float* __restrict__ W1, const float* __restrict__ W2,
    const float* __restrict__ Wc, short* __restrict__ wt,
    int nS1, int nConv) {
  int b = blockIdx.x;
  int tid = threadIdx.x;
  if (b < nS1) {
    // s1: bucket histogram (bucket = dst >> 7)
    __shared__ int h[NBMAX];
    for (int i = tid; i < NBMAX; i += 256) h[i] = 0;
    __syncthreads();
    int i0 = b * CHUNK;
    int i1 = min(i0 + CHUNK, e);
    for (int i = i0 + tid; i < i1; i += 256) atomicAdd(&h[dst[i] >> 7], 1);
    __syncthreads();
    for (int i = tid; i < NBMAX; i += 256)
      if (h[i]) atomicAdd(&bucketCount[i], h[i]);
  } else if (b < nS1 + nConv) {
    // conv: f32 -> packed bf16x2, plus zero row at node N
    int i = (b - nS1) * 256 + tid;
    if (i < n64) {
      float2 v = ((const float2*)x)[i];
      hb[i] = packbf(v.x, v.y);
    } else if (i < total64) {
      hb[i] = 0u;
    }
  } else {
    // prep: bf16 weights, pre-swizzled [col][k] images; W1/W2 x3 layers + Wc
    int idx = (b - nS1 - nConv) * 256 + tid;
    if (idx < 3 * 2 * 16384) {
      int lm = idx >> 14;
      int e2 = idx & 16383;
      int k = e2 >> 7;
      int col = e2 & 127;
      int layer = lm >> 1, mat = lm & 1;
      const float* W = mat ? W2 : W1;
      float w = W[layer * 16384 + k * 128 + col];
      int ksw = k ^ ((col & 7) << 3);
      wt[(size_t)lm * 16384 + col * 128 + ksw] = (short)bf16rne(w);
    } else if (idx < 3 * 2 * 16384 + 2048) {
      int e2 = idx - 3 * 2 * 16384;
      int k = e2 >> 4;
      int col = e2 & 15;
      float w = Wc[k * 16 + col];
      int ksw = k ^ ((col & 7) << 3);
      wt[(size_t)6 * 16384 + col * 128 + ksw] = (short)bf16rne(w);
    }
  }
}

// ---------- S2: scan bucket counts ----------
__global__ __launch_bounds__(256) void s2_scan(const int* __restrict__ bucketCount,
                                               int* __restrict__ bucketOff,
                                               int* __restrict__ gCursor,
                                               int* __restrict__ rs, int nb, int n, int e) {
  __shared__ int cnt[NBMAX], inc[NBMAX];
  int tid = threadIdx.x;
  for (int i = tid; i < nb; i += 256) cnt[i] = bucketCount[i];
  __syncthreads();
  block_scan_incl(cnt, inc, nb, tid);
  for (int i = tid; i < nb; i += 256) {
    int off = inc[i] - cnt[i];
    bucketOff[i] = off;
    gCursor[i] = off;
  }
  if (tid == 0) { bucketOff[nb] = e; rs[n] = e; }
}

// ---------- S3: block-local grouping + coalesced bucket scatter ----------
__global__ __launch_bounds__(256) void s3_scatter(const int* __restrict__ src,
                                                  const int* __restrict__ dst,
                                                  int* __restrict__ gCursor,
                                                  unsigned int* __restrict__ bucketed,
                                                  int e, int nb) {
  __shared__ int cnt[NBMAX], inc[NBMAX], base[NBMAX], cur[NBMAX];
  __shared__ unsigned int pairs[CHUNK];
  int tid = threadIdx.x;
  for (int i = tid; i < nb; i += 256) cnt[i] = 0;
  __syncthreads();
  int i0 = blockIdx.x * CHUNK;
  int i1 = min(i0 + CHUNK, e);
  for (int i = i0 + tid; i < i1; i += 256) atomicAdd(&cnt[dst[i] >> 7], 1);
  __syncthreads();
  block_scan_incl(cnt, inc, nb, tid);
  for (int b = tid; b < nb; b += 256) {
    int c = cnt[b];
    base[b] = c ? atomicAdd(&gCursor[b], c) : 0;
    cur[b] = inc[b] - c;
  }
  __syncthreads();
  for (int i = i0 + tid; i < i1; i += 256) {
    int d = dst[i];
    int p = atomicAdd(&cur[d >> 7], 1);
    pairs[p] = (unsigned)d | ((unsigned)src[i] << 16);
  }
  __syncthreads();
  int m = i1 - i0;
  for (int i = tid; i < m; i += 256) {
    unsigned w = pairs[i];
    int b = (int)(w & 0xFFFFu) >> 7;
    bucketed[base[b] + (i - (inc[b] - cnt[b]))] = w;
  }
}

// ---------- S4: per-bucket fill of PADDED ssrc (multiple of 8, min 8) ----------
__global__ __launch_bounds__(256) void s4_fill(const unsigned int* __restrict__ bucketed,
                                               const int* __restrict__ bucketOff,
                                               int* __restrict__ rs,
                                               unsigned short* __restrict__ pdeg,
                                               unsigned short* __restrict__ ssrc, int n) {
  __shared__ int cnt[128], pin[128], cur[128];
  __shared__ unsigned short outb[SCAP];
  int b = blockIdx.x;
  int bo = bucketOff[b], b1 = bucketOff[b + 1];
  int len = b1 - bo;
  int pstart = bo + b * PADSLACK;
  int tid = threadIdx.x;
  int n0 = b << 7;
  if (tid < 128) cnt[tid] = 0;
  __syncthreads();
  for (int i = tid; i < len; i += 256) atomicAdd(&cnt[bucketed[bo + i] & 127], 1);
  __syncthreads();
  int pc = 0;
  if (tid < 128) {
    pc = max(8, (cnt[tid] + 7) & ~7);
    pin[tid] = pc;
  }
  __syncthreads();
  for (int d = 1; d < 128; d <<= 1) {
    int v = 0;
    if (tid < 128 && tid >= d) v = pin[tid - d];
    __syncthreads();
    if (tid < 128) pin[tid] += v;
    __syncthreads();
  }
  int plen = pin[127];
  if (tid < 128) {
    int off = pin[tid] - pc;
    cur[tid] = off;
    int node = n0 + tid;
    if (node < n) {
      rs[node] = pstart + off;
      pdeg[node] = (unsigned short)pc;
    }
  }
  __syncthreads();
  if (plen <= SCAP) {
    for (int i = tid; i < plen; i += 256) outb[i] = (unsigned short)n;
    __syncthreads();
    for (int i = tid; i < len; i += 256) {
      unsigned w = bucketed[bo + i];
      int p = atomicAdd(&cur[w & 127], 1);
      outb[p] = (unsigned short)(w >> 16);
    }
    __syncthreads();
    for (int i = tid; i < plen; i += 256) ssrc[pstart + i] = outb[i];
  } else {
    for (int i = tid; i < plen; i += 256) ssrc[pstart + i] = (unsigned short)n;
    __syncthreads();
    for (int i = tid; i < len; i += 256) {
      unsigned w = bucketed[bo + i];
      int p = atomicAdd(&cur[w & 127], 1);
      ssrc[pstart + p] = (unsigned short)(w >> 16);
    }
  }
}

// ---------- aggregation: 2 nodes per wave, interleaved depth-8 streams ----------
// Each stream = 1 node (round-9 pattern); the two streams cover each other's
// pipeline drain and halve per-node setup. Pads point at zero row hb[n].
__global__ __launch_bounds__(256) void gather_zb(const unsigned int* __restrict__ hb,
                                                 const int* __restrict__ rs,
                                                 const unsigned short* __restrict__ pdeg,
                                                 const unsigned short* __restrict__ ssrc,
                                                 unsigned int* __restrict__ zb, int n) {
  int pair = blockIdx.x * 4 + (threadIdx.x >> 6);
  int nA = pair * 2;
  if (nA >= n) return;
  int nB = nA + 1;
  bool hasB = nB < n;
  int lane = threadIdx.x & 63;
  int sA = rs[nA], mA = pdeg[nA];
  int sB = hasB ? rs[nB] : sA;
  int mB = hasB ? pdeg[nB] : 0;

  unsigned vA = hb[(unsigned)nA * 64u + lane];
  float ax0 = bflo(vA), ay0 = bfhi(vA);
  float ax1 = 0.f, ay1 = 0.f;
  if (hasB) {
    unsigned vB = hb[(unsigned)nB * 64u + lane];
    ax1 = bflo(vB); ay1 = bfhi(vB);
  }

  unsigned A0[8], B0[8], A1[8], B1[8];
#pragma unroll
  for (int i = 0; i < 8; ++i) A0[i] = hb[(unsigned)ssrc[sA + i] * 64u + lane];
  if (hasB) {
#pragma unroll
    for (int i = 0; i < 8; ++i) A1[i] = hb[(unsigned)ssrc[sB + i] * 64u + lane];
  }
  int iA = sA + 8, eA = sA + mA;
  int iB = sB + 8, eB = sB + mB;

  if (hasB) {
    while (iA < eA && iB < eB) {
#pragma unroll
      for (int i = 0; i < 8; ++i) B0[i] = hb[(unsigned)ssrc[iA + i] * 64u + lane];
#pragma unroll
      for (int i = 0; i < 8; ++i) B1[i] = hb[(unsigned)ssrc[iB + i] * 64u + lane];
#pragma unroll
      for (int i = 0; i < 8; ++i) {
        ax0 += bflo(A0[i]); ay0 += bfhi(A0[i]); A0[i] = B0[i];
      }
#pragma unroll
      for (int i = 0; i < 8; ++i) {
        ax1 += bflo(A1[i]); ay1 += bfhi(A1[i]); A1[i] = B1[i];
      }
      iA += 8; iB += 8;
    }
  }
  while (iA < eA) {
#pragma unroll
    for (int i = 0; i < 8; ++i) B0[i] = hb[(unsigned)ssrc[iA + i] * 64u + lane];
#pragma unroll
    for (int i = 0; i < 8; ++i) {
      ax0 += bflo(A0[i]); ay0 += bfhi(A0[i]); A0[i] = B0[i];
    }
    iA += 8;
  }
#pragma unroll
  for (int i = 0; i < 8; ++i) { ax0 += bflo(A0[i]); ay0 += bfhi(A0[i]); }
  zb[(unsigned)nA * 64u + lane] = packbf(ax0, ay0);

  if (hasB) {
    while (iB < eB) {
#pragma unroll
      for (int i = 0; i < 8; ++i) B1[i] = hb[(unsigned)ssrc[iB + i] * 64u + lane];
#pragma unroll
      for (int i = 0; i < 8; ++i) {
        ax1 += bflo(A1[i]); ay1 += bfhi(A1[i]); A1[i] = B1[i];
      }
      iB += 8;
    }
#pragma unroll
    for (int i = 0; i < 8; ++i) { ax1 += bflo(A1[i]); ay1 += bfhi(A1[i]); }
    zb[(unsigned)nB * 64u + lane] = packbf(ax1, ay1);
  }
}

// ---------- MFMA MLP (+ optional MFMA classifier tail) ----------
// 256 threads = 4 waves in 2x2. W2 reg-staged async during transpose (T14).
__global__ __launch_bounds__(256, 2) void mlp_mfma(
    const unsigned int* __restrict__ zb,
    const short* __restrict__ Wt1, const short* __restrict__ Wt2,
    const float* __restrict__ b1, const float* __restrict__ b2,
    float* __restrict__ fout, unsigned short* __restrict__ hbout,
    const short* __restrict__ WcI, const float* __restrict__ bc,
    float* __restrict__ lout, int n) {
  __shared__ char wbuf[32768];
  __shared__ char hsb[128 * 256];
  int tid = threadIdx.x;
  int w = tid >> 6, lane = tid & 63;
  int lr = lane & 15, hi = lane >> 4;
  int wr = (w & 1) * 64;
  int wc = (w >> 1) * 64;
  int node0 = blockIdx.x * 128;

  bf16x8 a[4][4];
#pragma unroll
  for (int t = 0; t < 4; ++t) {
    int row = node0 + wr + t * 16 + lr;
    row = min(row, n - 1);
    const char* rp = (const char*)(zb + (size_t)row * 64);
#pragma unroll
    for (int ks = 0; ks < 4; ++ks)
      a[t][ks] = *(const bf16x8*)(rp + ks * 64 + hi * 16);
  }

  f32x4 acc[4][4];
#pragma unroll
  for (int ct = 0; ct < 4; ++ct) {
    float bb = b1[wc + ct * 16 + lr];
#pragma unroll
    for (int t = 0; t < 4; ++t) acc[t][ct] = (f32x4){bb, bb, bb, bb};
  }

  // stage W1 -> LDS
  {
    const char* gs = (const char*)Wt1;
    for (int i = tid * 16; i < 32768; i += 256 * 16)
      *(float4*)&wbuf[i] = *(const float4*)(gs + i);
  }
  __syncthreads();
#pragma unroll
  for (int ct = 0; ct < 4; ++ct) {
    int col = wc + ct * 16 + lr;
    int cx = (col & 7) << 4;
#pragma unroll
    for (int ks = 0; ks < 4; ++ks) {
      bf16x8 b = *(const bf16x8*)&wbuf[(col * 256 + ks * 64 + hi * 16) ^ cx];
#pragma unroll
      for (int t = 0; t < 4; ++t)
        acc[t][ct] = __builtin_amdgcn_mfma_f32_16x16x32_bf16(a[t][ks], b, acc[t][ct], 0, 0, 0);
    }
  }

  // issue W2 global->reg loads (latency hides under transpose phase)
  float4 w2r[8];
#pragma unroll
  for (int i = 0; i < 8; ++i)
    w2r[i] = *(const float4*)((const char*)Wt2 + tid * 16 + i * 4096);

  // relu -> swizzled LDS bf16
#pragma unroll
  for (int t = 0; t < 4; ++t)
#pragma unroll
    for (int ct = 0; ct < 4; ++ct)
#pragma unroll
      for (int r = 0; r < 4; ++r) {
        int row = wr + t * 16 + hi * 4 + r;
        int col = wc + ct * 16 + lr;
        float v = fmaxf(acc[t][ct][r], 0.f);
        int byte = (row * 256 + col * 2) ^ ((row & 7) << 4);
        *(unsigned short*)&hsb[byte] = (unsigned short)bf16rne(v);
      }
  __syncthreads();

  bf16x8 a2[4][4];
#pragma unroll
  for (int t = 0; t < 4; ++t) {
    int row = wr + t * 16 + lr;
    int xr = (row & 7) << 4;
#pragma unroll
    for (int ks = 0; ks < 4; ++ks)
      a2[t][ks] = *(const bf16x8*)&hsb[(row * 256 + ks * 64 + hi * 16) ^ xr];
  }
  // write staged W2 into wbuf (all W1 reads finished before previous barrier)
#pragma unroll
  for (int i = 0; i < 8; ++i)
    *(float4*)&wbuf[tid * 16 + i * 4096] = w2r[i];

#pragma unroll
  for (int ct = 0; ct < 4; ++ct) {
    float bb = b2[wc + ct * 16 + lr];
#pragma unroll
    for (int t = 0; t < 4; ++t) acc[t][ct] = (f32x4){bb, bb, bb, bb};
  }
  __syncthreads();

#pragma unroll
  for (int ct = 0; ct < 4; ++ct) {
    int col = wc + ct * 16 + lr;
    int cx = (col & 7) << 4;
#pragma unroll
    for (int ks = 0; ks < 4; ++ks) {
      bf16x8 b = *(const bf16x8*)&wbuf[(col * 256 + ks * 64 + hi * 16) ^ cx];
#pragma unroll
      for (int t = 0; t < 4; ++t)
        acc[t][ct] = __builtin_amdgcn_mfma_f32_16x16x32_bf16(a2[t][ks], b, acc[t][ct], 0, 0, 0);
    }
  }

#pragma unroll
  for (int t = 0; t < 4; ++t)
#pragma unroll
    for (int ct = 0; ct < 4; ++ct)
#pragma unroll
      for (int r = 0; r < 4; ++r) {
        int node = node0 + wr + t * 16 + hi * 4 + r;
        if (node < n) {
          int col = wc + ct * 16 + lr;
          float v = acc[t][ct][r];
          if (fout) fout[(size_t)node * DD + col] = v;
          if (hbout) hbout[(size_t)node * DD + col] = (unsigned short)bf16rne(v);
        }
      }

  // ---- fused MFMA classifier tail (layer 2 only): logits = h @ Wc + bc ----
  if (lout) {
    // write final h (bf16) into swizzled hsb; safe: all a2 reads done pre-barrier
#pragma unroll
    for (int t = 0; t < 4; ++t)
#pragma unroll
      for (int ct = 0; ct < 4; ++ct)
#pragma unroll
        for (int r = 0; r < 4; ++r) {
          int row = wr + t * 16 + hi * 4 + r;
          int col = wc + ct * 16 + lr;
          int byte = (row * 256 + col * 2) ^ ((row & 7) << 4);
          *(unsigned short*)&hsb[byte] = (unsigned short)bf16rne(acc[t][ct][r]);
        }
    __syncthreads();
    bf16x8 a3[4][4];
#pragma unroll
    for (int t = 0; t < 4; ++t) {
      int row = wr + t * 16 + lr;
      int xr = (row & 7) << 4;
#pragma unroll
      for (int ks = 0; ks < 4; ++ks)
        a3[t][ks] = *(const bf16x8*)&hsb[(row * 256 + ks * 64 + hi * 16) ^ xr];
    }
    // Wc B-frags straight from global image (4KB, L1-hot)
    const char* wci = (const char*)WcI;
    bf16x8 bw[4];
    int cxc = (lr & 7) << 4;
#pragma unroll
    for (int ks = 0; ks < 4; ++ks)
      bw[ks] = *(const bf16x8*)&wci[(lr * 256 + ks * 64 + hi * 16) ^ cxc];
    f32x4 acc3[4];
    float bb = bc[lr];
#pragma unroll
    for (int t = 0; t < 4; ++t) acc3[t] = (f32x4){bb, bb, bb, bb};
#pragma unroll
    for (int t = 0; t < 4; ++t)
#pragma unroll
      for (int ks = 0; ks < 4; ++ks)
        acc3[t] = __builtin_amdgcn_mfma_f32_16x16x32_bf16(a3[t][ks], bw[ks], acc3[t], 0, 0, 0);
#pragma unroll
    for (int t = 0; t < 4; ++t)
#pragma unroll
      for (int r = 0; r < 4; ++r) {
        int gn = node0 + wr + t * 16 + hi * 4 + r;
        if (gn < n) lout[(size_t)gn * 16 + lr] = acc3[t][r];
      }
  }
}

extern "C" void kernel_launch(void* const* d_in, const int* in_sizes, int n_in,
                              void* d_out, int out_size, void* d_ws, size_t ws_size,
                              hipStream_t stream) {
  const float* x = (const float*)d_in[0];
  const int* ei = (const int*)d_in[1];
  const float* W1 = (const float*)d_in[2];
  const float* b1 = (const float*)d_in[3];
  const float* W2 = (const float*)d_in[4];
  const float* b2 = (const float*)d_in[5];
  const float* Wc = (const float*)d_in[6];
  const float* bc = (const float*)d_in[7];

  const int N = in_sizes[0] / DD;
  const int E = in_sizes[1] / 2;
  const int* src = ei;
  const int* dst = ei + E;
  const int NB = (N + 127) >> 7;

  float* outp = (float*)d_out;
  float* h_final = outp;
  float* logits = outp + (size_t)N * DD;

  char* ws = (char*)d_ws;
  size_t off = 0;
  auto alloc = [&](size_t bytes) {
    char* p = ws + off;
    off = (off + bytes + 255) & ~(size_t)255;
    return p;
  };
  unsigned int* zb = (unsigned int*)alloc((size_t)N * 64 * 4);
  unsigned int* hb = (unsigned int*)alloc((size_t)(N + 1) * 64 * 4);
  short* wt = (short*)alloc((size_t)(3 * 2 * 16384 + 2048) * 2);  // W images + Wc image
  int* bucketCount = (int*)alloc(NBMAX * 4);
  int* bucketOff = (int*)alloc((NBMAX + 1) * 4);
  int* gCursor = (int*)alloc(NBMAX * 4);
  int* rs = (int*)alloc((size_t)(N + 1) * 4);
  unsigned short* pdeg = (unsigned short*)alloc((size_t)N * 2);
  unsigned int* bucketed = (unsigned int*)alloc((size_t)E * 4);
  unsigned short* ssrc = (unsigned short*)alloc(((size_t)E + (size_t)NB * PADSLACK) * 2);

  const int gEdge = (E + CHUNK - 1) / CHUNK;
  const int gGather = ((N + 1) / 2 + 3) / 4;  // 2 nodes per wave
  const int gMlp = (N + 127) / 128;
  const int total64 = (N + 1) * 64;
  const int nConv = (total64 + 255) / 256;
  const int nPrep = (3 * 2 * 16384 + 2048 + 255) / 256;

  hipMemsetAsync(bucketCount, 0, NBMAX * 4, stream);
  // fat setup: s1 histogram + conv bf16 + weight prep in one launch
  setup_fat<<<gEdge + nConv + nPrep, 256, 0, stream>>>(
      dst, bucketCount, E, x, hb, N * 64, total64, W1, W2, Wc, wt, gEdge, nConv);
  s2_scan<<<1, 256, 0, stream>>>(bucketCount, bucketOff, gCursor, rs, NB, N, E);
  s3_scatter<<<gEdge, 256, 0, stream>>>(src, dst, gCursor, bucketed, E, NB);
  s4_fill<<<NB, 256, 0, stream>>>(bucketed, bucketOff, rs, pdeg, ssrc, N);

  auto WT = [&](int layer, int mat) { return wt + ((size_t)(layer * 2 + mat)) * 16384; };
  const short* WcI = wt + (size_t)6 * 16384;

  // layer 0
  gather_zb<<<gGather, 256, 0, stream>>>(hb, rs, pdeg, ssrc, zb, N);
  mlp_mfma<<<gMlp, 256, 0, stream>>>(zb, WT(0, 0), WT(0, 1), b1, b2,
                                     nullptr, (unsigned short*)hb, nullptr, nullptr, nullptr, N);
  // layer 1
  gather_zb<<<gGather, 256, 0, stream>>>(hb, rs, pdeg, ssrc, zb, N);
  mlp_mfma<<<gMlp, 256, 0, stream>>>(zb, WT(1, 0), WT(1, 1), b1 + DD, b2 + DD,
                                     nullptr, (unsigned short*)hb, nullptr, nullptr, nullptr, N);
  // layer 2 -> f32 h + fused MFMA classifier -> logits
  gather_zb<<<gGather, 256, 0, stream>>>(hb, rs, pdeg, ssrc, zb, N);
  mlp_mfma<<<gMlp, 256, 0, stream>>>(zb, WT(2, 0), WT(2, 1), b1 + 2 * DD, b2 + 2 * DD,
                                     h_final, nullptr, WcI, bc, logits, N);
}

// Round 14
// 260.481 us; speedup vs baseline: 1.5361x; 1.0099x over previous
//
#include <hip/hip_runtime.h>

#define DD 128
#define CHUNK 6144    // edges per block in S1/S3
#define NBMAX 512     // max buckets (N <= 65536)
#define SCAP 8192     // per-bucket LDS staging capacity
#define PADSLACK 1024 // max padding per bucket (128 nodes x 8)

typedef __attribute__((ext_vector_type(8))) short bf16x8;
typedef __attribute__((ext_vector_type(4))) float f32x4;

// ---------- bf16 helpers ----------
__device__ __forceinline__ unsigned bf16rne(float f) {
  unsigned u = __float_as_uint(f);
  return (u + 0x7FFFu + ((u >> 16) & 1u)) >> 16;
}
__device__ __forceinline__ unsigned packbf(float lo, float hi) {
  return bf16rne(lo) | (bf16rne(hi) << 16);
}
__device__ __forceinline__ float bflo(unsigned v) { return __uint_as_float(v << 16); }
__device__ __forceinline__ float bfhi(unsigned v) { return __uint_as_float(v & 0xFFFF0000u); }

// ---------- inclusive block scan over LDS array (256 threads, nb <= 512) ----------
__device__ void block_scan_incl(int* cnt, int* inc, int nb, int tid) {
  for (int i = tid; i < nb; i += 256) inc[i] = cnt[i];
  __syncthreads();
  for (int d = 1; d < nb; d <<= 1) {
    int i0 = tid, i1 = tid + 256;
    int v0 = 0, v1 = 0;
    if (i0 < nb && i0 >= d) v0 = inc[i0 - d];
    if (i1 < nb && i1 >= d) v1 = inc[i1 - d];
    __syncthreads();
    if (i0 < nb) inc[i0] += v0;
    if (i1 < nb) inc[i1] += v1;
    __syncthreads();
  }
}

// ---------- fat setup kernel: [s1 hist | conv bf16 | prep W+Wc] by block range ----------
__global__ __launch_bounds__(256) void setup_fat(
    const int* __restrict__ dst, int* __restrict__ bucketCount, int e,
    const float* __restrict__ x, unsigned int* __restrict__ hb, int n64, int total64,
    const float* __restrict__ W1, const float* __restrict__ W2,
    const float* __restrict__ Wc, short* __restrict__ wt,
    int nS1, int nConv) {
  int b = blockIdx.x;
  int tid = threadIdx.x;
  if (b < nS1) {
    __shared__ int h[NBMAX];
    for (int i = tid; i < NBMAX; i += 256) h[i] = 0;
    __syncthreads();
    int i0 = b * CHUNK;
    int i1 = min(i0 + CHUNK, e);
    for (int i = i0 + tid; i < i1; i += 256) atomicAdd(&h[dst[i] >> 7], 1);
    __syncthreads();
    for (int i = tid; i < NBMAX; i += 256)
      if (h[i]) atomicAdd(&bucketCount[i], h[i]);
  } else if (b < nS1 + nConv) {
    int i = (b - nS1) * 256 + tid;
    if (i < n64) {
      float2 v = ((const float2*)x)[i];
      hb[i] = packbf(v.x, v.y);
    } else if (i < total64) {
      hb[i] = 0u;
    }
  } else {
    int idx = (b - nS1 - nConv) * 256 + tid;
    if (idx < 3 * 2 * 16384) {
      int lm = idx >> 14;
      int e2 = idx & 16383;
      int k = e2 >> 7;
      int col = e2 & 127;
      int layer = lm >> 1, mat = lm & 1;
      const float* W = mat ? W2 : W1;
      float w = W[layer * 16384 + k * 128 + col];
      int ksw = k ^ ((col & 7) << 3);
      wt[(size_t)lm * 16384 + col * 128 + ksw] = (short)bf16rne(w);
    } else if (idx < 3 * 2 * 16384 + 2048) {
      int e2 = idx - 3 * 2 * 16384;
      int k = e2 >> 4;
      int col = e2 & 15;
      float w = Wc[k * 16 + col];
      int ksw = k ^ ((col & 7) << 3);
      wt[(size_t)6 * 16384 + col * 128 + ksw] = (short)bf16rne(w);
    }
  }
}

// ---------- S2: scan bucket counts ----------
__global__ __launch_bounds__(256) void s2_scan(const int* __restrict__ bucketCount,
                                               int* __restrict__ bucketOff,
                                               int* __restrict__ gCursor,
                                               int* __restrict__ rs, int nb, int n, int e) {
  __shared__ int cnt[NBMAX], inc[NBMAX];
  int tid = threadIdx.x;
  for (int i = tid; i < nb; i += 256) cnt[i] = bucketCount[i];
  __syncthreads();
  block_scan_incl(cnt, inc, nb, tid);
  for (int i = tid; i < nb; i += 256) {
    int off = inc[i] - cnt[i];
    bucketOff[i] = off;
    gCursor[i] = off;
  }
  if (tid == 0) { bucketOff[nb] = e; rs[n] = e; }
}

// ---------- S3: block-local grouping + coalesced bucket scatter ----------
__global__ __launch_bounds__(256) void s3_scatter(const int* __restrict__ src,
                                                  const int* __restrict__ dst,
                                                  int* __restrict__ gCursor,
                                                  unsigned int* __restrict__ bucketed,
                                                  int e, int nb) {
  __shared__ int cnt[NBMAX], inc[NBMAX], base[NBMAX], cur[NBMAX];
  __shared__ unsigned int pairs[CHUNK];
  int tid = threadIdx.x;
  for (int i = tid; i < nb; i += 256) cnt[i] = 0;
  __syncthreads();
  int i0 = blockIdx.x * CHUNK;
  int i1 = min(i0 + CHUNK, e);
  for (int i = i0 + tid; i < i1; i += 256) atomicAdd(&cnt[dst[i] >> 7], 1);
  __syncthreads();
  block_scan_incl(cnt, inc, nb, tid);
  for (int b = tid; b < nb; b += 256) {
    int c = cnt[b];
    base[b] = c ? atomicAdd(&gCursor[b], c) : 0;
    cur[b] = inc[b] - c;
  }
  __syncthreads();
  for (int i = i0 + tid; i < i1; i += 256) {
    int d = dst[i];
    int p = atomicAdd(&cur[d >> 7], 1);
    pairs[p] = (unsigned)d | ((unsigned)src[i] << 16);
  }
  __syncthreads();
  int m = i1 - i0;
  for (int i = tid; i < m; i += 256) {
    unsigned w = pairs[i];
    int b = (int)(w & 0xFFFFu) >> 7;
    bucketed[base[b] + (i - (inc[b] - cnt[b]))] = w;
  }
}

// ---------- S4: per-bucket fill of PADDED ssrc (multiple of 8, min 8) ----------
__global__ __launch_bounds__(256) void s4_fill(const unsigned int* __restrict__ bucketed,
                                               const int* __restrict__ bucketOff,
                                               int* __restrict__ rs,
                                               unsigned short* __restrict__ pdeg,
                                               unsigned short* __restrict__ ssrc, int n) {
  __shared__ int cnt[128], pin[128], cur[128];
  __shared__ unsigned short outb[SCAP];
  int b = blockIdx.x;
  int bo = bucketOff[b], b1 = bucketOff[b + 1];
  int len = b1 - bo;
  int pstart = bo + b * PADSLACK;
  int tid = threadIdx.x;
  int n0 = b << 7;
  if (tid < 128) cnt[tid] = 0;
  __syncthreads();
  for (int i = tid; i < len; i += 256) atomicAdd(&cnt[bucketed[bo + i] & 127], 1);
  __syncthreads();
  int pc = 0;
  if (tid < 128) {
    pc = max(8, (cnt[tid] + 7) & ~7);
    pin[tid] = pc;
  }
  __syncthreads();
  for (int d = 1; d < 128; d <<= 1) {
    int v = 0;
    if (tid < 128 && tid >= d) v = pin[tid - d];
    __syncthreads();
    if (tid < 128) pin[tid] += v;
    __syncthreads();
  }
  int plen = pin[127];
  if (tid < 128) {
    int off = pin[tid] - pc;
    cur[tid] = off;
    int node = n0 + tid;
    if (node < n) {
      rs[node] = pstart + off;
      pdeg[node] = (unsigned short)pc;
    }
  }
  __syncthreads();
  if (plen <= SCAP) {
    for (int i = tid; i < plen; i += 256) outb[i] = (unsigned short)n;
    __syncthreads();
    for (int i = tid; i < len; i += 256) {
      unsigned w = bucketed[bo + i];
      int p = atomicAdd(&cur[w & 127], 1);
      outb[p] = (unsigned short)(w >> 16);
    }
    __syncthreads();
    for (int i = tid; i < plen; i += 256) ssrc[pstart + i] = outb[i];
  } else {
    for (int i = tid; i < plen; i += 256) ssrc[pstart + i] = (unsigned short)n;
    __syncthreads();
    for (int i = tid; i < len; i += 256) {
      unsigned w = bucketed[bo + i];
      int p = atomicAdd(&cur[w & 127], 1);
      ssrc[pstart + p] = (unsigned short)(w >> 16);
    }
  }
}

// ---------- aggregation: 1 node/wave, 2-wave (128-thread) blocks, depth-8 ----------
// Round-9 body; smaller blocks reduce wave-slot holding from degree imbalance.
__global__ __launch_bounds__(128) void gather_zb(const unsigned int* __restrict__ hb,
                                                 const int* __restrict__ rs,
                                                 const unsigned short* __restrict__ pdeg,
                                                 const unsigned short* __restrict__ ssrc,
                                                 unsigned int* __restrict__ zb, int n) {
  int node = blockIdx.x * 2 + (threadIdx.x >> 6);
  if (node >= n) return;
  int lane = threadIdx.x & 63;
  int s0 = rs[node];
  int m = pdeg[node];
  unsigned v = hb[(unsigned)node * 64u + lane];
  float ax = bflo(v), ay = bfhi(v);
  unsigned A[8], B[8];
#pragma unroll
  for (int i = 0; i < 8; ++i)
    A[i] = hb[(unsigned)ssrc[s0 + i] * 64u + lane];
  int t1 = s0 + m;
  for (int t = s0 + 8; t < t1; t += 8) {
#pragma unroll
    for (int i = 0; i < 8; ++i)
      B[i] = hb[(unsigned)ssrc[t + i] * 64u + lane];
#pragma unroll
    for (int i = 0; i < 8; ++i) {
      ax += bflo(A[i]);
      ay += bfhi(A[i]);
    }
#pragma unroll
    for (int i = 0; i < 8; ++i) A[i] = B[i];
  }
#pragma unroll
  for (int i = 0; i < 8; ++i) {
    ax += bflo(A[i]);
    ay += bfhi(A[i]);
  }
  zb[(unsigned)node * 64u + lane] = packbf(ax, ay);
}

// ---------- MFMA MLP (+ optional MFMA classifier tail) ----------
__global__ __launch_bounds__(256, 2) void mlp_mfma(
    const unsigned int* __restrict__ zb,
    const short* __restrict__ Wt1, const short* __restrict__ Wt2,
    const float* __restrict__ b1, const float* __restrict__ b2,
    float* __restrict__ fout, unsigned short* __restrict__ hbout,
    const short* __restrict__ WcI, const float* __restrict__ bc,
    float* __restrict__ lout, int n) {
  __shared__ char wbuf[32768];
  __shared__ char hsb[128 * 256];
  int tid = threadIdx.x;
  int w = tid >> 6, lane = tid & 63;
  int lr = lane & 15, hi = lane >> 4;
  int wr = (w & 1) * 64;
  int wc = (w >> 1) * 64;
  int node0 = blockIdx.x * 128;

  bf16x8 a[4][4];
#pragma unroll
  for (int t = 0; t < 4; ++t) {
    int row = node0 + wr + t * 16 + lr;
    row = min(row, n - 1);
    const char* rp = (const char*)(zb + (size_t)row * 64);
#pragma unroll
    for (int ks = 0; ks < 4; ++ks)
      a[t][ks] = *(const bf16x8*)(rp + ks * 64 + hi * 16);
  }

  f32x4 acc[4][4];
#pragma unroll
  for (int ct = 0; ct < 4; ++ct) {
    float bb = b1[wc + ct * 16 + lr];
#pragma unroll
    for (int t = 0; t < 4; ++t) acc[t][ct] = (f32x4){bb, bb, bb, bb};
  }

  {
    const char* gs = (const char*)Wt1;
    for (int i = tid * 16; i < 32768; i += 256 * 16)
      *(float4*)&wbuf[i] = *(const float4*)(gs + i);
  }
  __syncthreads();
#pragma unroll
  for (int ct = 0; ct < 4; ++ct) {
    int col = wc + ct * 16 + lr;
    int cx = (col & 7) << 4;
#pragma unroll
    for (int ks = 0; ks < 4; ++ks) {
      bf16x8 b = *(const bf16x8*)&wbuf[(col * 256 + ks * 64 + hi * 16) ^ cx];
#pragma unroll
      for (int t = 0; t < 4; ++t)
        acc[t][ct] = __builtin_amdgcn_mfma_f32_16x16x32_bf16(a[t][ks], b, acc[t][ct], 0, 0, 0);
    }
  }

  float4 w2r[8];
#pragma unroll
  for (int i = 0; i < 8; ++i)
    w2r[i] = *(const float4*)((const char*)Wt2 + tid * 16 + i * 4096);

#pragma unroll
  for (int t = 0; t < 4; ++t)
#pragma unroll
    for (int ct = 0; ct < 4; ++ct)
#pragma unroll
      for (int r = 0; r < 4; ++r) {
        int row = wr + t * 16 + hi * 4 + r;
        int col = wc + ct * 16 + lr;
        float v = fmaxf(acc[t][ct][r], 0.f);
        int byte = (row * 256 + col * 2) ^ ((row & 7) << 4);
        *(unsigned short*)&hsb[byte] = (unsigned short)bf16rne(v);
      }
  __syncthreads();

  bf16x8 a2[4][4];
#pragma unroll
  for (int t = 0; t < 4; ++t) {
    int row = wr + t * 16 + lr;
    int xr = (row & 7) << 4;
#pragma unroll
    for (int ks = 0; ks < 4; ++ks)
      a2[t][ks] = *(const bf16x8*)&hsb[(row * 256 + ks * 64 + hi * 16) ^ xr];
  }
#pragma unroll
  for (int i = 0; i < 8; ++i)
    *(float4*)&wbuf[tid * 16 + i * 4096] = w2r[i];

#pragma unroll
  for (int ct = 0; ct < 4; ++ct) {
    float bb = b2[wc + ct * 16 + lr];
#pragma unroll
    for (int t = 0; t < 4; ++t) acc[t][ct] = (f32x4){bb, bb, bb, bb};
  }
  __syncthreads();

#pragma unroll
  for (int ct = 0; ct < 4; ++ct) {
    int col = wc + ct * 16 + lr;
    int cx = (col & 7) << 4;
#pragma unroll
    for (int ks = 0; ks < 4; ++ks) {
      bf16x8 b = *(const bf16x8*)&wbuf[(col * 256 + ks * 64 + hi * 16) ^ cx];
#pragma unroll
      for (int t = 0; t < 4; ++t)
        acc[t][ct] = __builtin_amdgcn_mfma_f32_16x16x32_bf16(a2[t][ks], b, acc[t][ct], 0, 0, 0);
    }
  }

#pragma unroll
  for (int t = 0; t < 4; ++t)
#pragma unroll
    for (int ct = 0; ct < 4; ++ct)
#pragma unroll
      for (int r = 0; r < 4; ++r) {
        int node = node0 + wr + t * 16 + hi * 4 + r;
        if (node < n) {
          int col = wc + ct * 16 + lr;
          float v = acc[t][ct][r];
          if (fout) fout[(size_t)node * DD + col] = v;
          if (hbout) hbout[(size_t)node * DD + col] = (unsigned short)bf16rne(v);
        }
      }

  if (lout) {
#pragma unroll
    for (int t = 0; t < 4; ++t)
#pragma unroll
      for (int ct = 0; ct < 4; ++ct)
#pragma unroll
        for (int r = 0; r < 4; ++r) {
          int row = wr + t * 16 + hi * 4 + r;
          int col = wc + ct * 16 + lr;
          int byte = (row * 256 + col * 2) ^ ((row & 7) << 4);
          *(unsigned short*)&hsb[byte] = (unsigned short)bf16rne(acc[t][ct][r]);
        }
    __syncthreads();
    bf16x8 a3[4][4];
#pragma unroll
    for (int t = 0; t < 4; ++t) {
      int row = wr + t * 16 + lr;
      int xr = (row & 7) << 4;
#pragma unroll
      for (int ks = 0; ks < 4; ++ks)
        a3[t][ks] = *(const bf16x8*)&hsb[(row * 256 + ks * 64 + hi * 16) ^ xr];
    }
    const char* wci = (const char*)WcI;
    bf16x8 bw[4];
    int cxc = (lr & 7) << 4;
#pragma unroll
    for (int ks = 0; ks < 4; ++ks)
      bw[ks] = *(const bf16x8*)&wci[(lr * 256 + ks * 64 + hi * 16) ^ cxc];
    f32x4 acc3[4];
    float bb = bc[lr];
#pragma unroll
    for (int t = 0; t < 4; ++t) acc3[t] = (f32x4){bb, bb, bb, bb};
#pragma unroll
    for (int t = 0; t < 4; ++t)
#pragma unroll
      for (int ks = 0; ks < 4; ++ks)
        acc3[t] = __builtin_amdgcn_mfma_f32_16x16x32_bf16(a3[t][ks], bw[ks], acc3[t], 0, 0, 0);
#pragma unroll
    for (int t = 0; t < 4; ++t)
#pragma unroll
      for (int r = 0; r < 4; ++r) {
        int gn = node0 + wr + t * 16 + hi * 4 + r;
        if (gn < n) lout[(size_t)gn * 16 + lr] = acc3[t][r];
      }
  }
}

extern "C" void kernel_launch(void* const* d_in, const int* in_sizes, int n_in,
                              void* d_out, int out_size, void* d_ws, size_t ws_size,
                              hipStream_t stream) {
  const float* x = (const float*)d_in[0];
  const int* ei = (const int*)d_in[1];
  const float* W1 = (const float*)d_in[2];
  const float* b1 = (const float*)d_in[3];
  const float* W2 = (const float*)d_in[4];
  const float* b2 = (const float*)d_in[5];
  const float* Wc = (const float*)d_in[6];
  const float* bc = (const float*)d_in[7];

  const int N = in_sizes[0] / DD;
  const int E = in_sizes[1] / 2;
  const int* src = ei;
  const int* dst = ei + E;
  const int NB = (N + 127) >> 7;

  float* outp = (float*)d_out;
  float* h_final = outp;
  float* logits = outp + (size_t)N * DD;

  char* ws = (char*)d_ws;
  size_t off = 0;
  auto alloc = [&](size_t bytes) {
    char* p = ws + off;
    off = (off + bytes + 255) & ~(size_t)255;
    return p;
  };
  unsigned int* zb = (unsigned int*)alloc((size_t)N * 64 * 4);
  unsigned int* hb = (unsigned int*)alloc((size_t)(N + 1) * 64 * 4);
  short* wt = (short*)alloc((size_t)(3 * 2 * 16384 + 2048) * 2);
  int* bucketCount = (int*)alloc(NBMAX * 4);
  int* bucketOff = (int*)alloc((NBMAX + 1) * 4);
  int* gCursor = (int*)alloc(NBMAX * 4);
  int* rs = (int*)alloc((size_t)(N + 1) * 4);
  unsigned short* pdeg = (unsigned short*)alloc((size_t)N * 2);
  unsigned int* bucketed = (unsigned int*)alloc((size_t)E * 4);
  unsigned short* ssrc = (unsigned short*)alloc(((size_t)E + (size_t)NB * PADSLACK) * 2);

  const int gEdge = (E + CHUNK - 1) / CHUNK;
  const int gGather = (N + 1) / 2;  // 2 nodes/block, 1 per wave
  const int gMlp = (N + 127) / 128;
  const int total64 = (N + 1) * 64;
  const int nConv = (total64 + 255) / 256;
  const int nPrep = (3 * 2 * 16384 + 2048 + 255) / 256;

  hipMemsetAsync(bucketCount, 0, NBMAX * 4, stream);
  setup_fat<<<gEdge + nConv + nPrep, 256, 0, stream>>>(
      dst, bucketCount, E, x, hb, N * 64, total64, W1, W2, Wc, wt, gEdge, nConv);
  s2_scan<<<1, 256, 0, stream>>>(bucketCount, bucketOff, gCursor, rs, NB, N, E);
  s3_scatter<<<gEdge, 256, 0, stream>>>(src, dst, gCursor, bucketed, E, NB);
  s4_fill<<<NB, 256, 0, stream>>>(bucketed, bucketOff, rs, pdeg, ssrc, N);

  auto WT = [&](int layer, int mat) { return wt + ((size_t)(layer * 2 + mat)) * 16384; };
  const short* WcI = wt + (size_t)6 * 16384;

  // layer 0
  gather_zb<<<gGather, 128, 0, stream>>>(hb, rs, pdeg, ssrc, zb, N);
  mlp_mfma<<<gMlp, 256, 0, stream>>>(zb, WT(0, 0), WT(0, 1), b1, b2,
                                     nullptr, (unsigned short*)hb, nullptr, nullptr, nullptr, N);
  // layer 1
  gather_zb<<<gGather, 128, 0, stream>>>(hb, rs, pdeg, ssrc, zb, N);
  mlp_mfma<<<gMlp, 256, 0, stream>>>(zb, WT(1, 0), WT(1, 1), b1 + DD, b2 + DD,
                                     nullptr, (unsigned short*)hb, nullptr, nullptr, nullptr, N);
  // layer 2 -> f32 h + fused MFMA classifier -> logits
  gather_zb<<<gGather, 128, 0, stream>>>(hb, rs, pdeg, ssrc, zb, N);
  mlp_mfma<<<gMlp, 256, 0, stream>>>(zb, WT(2, 0), WT(2, 1), b1 + 2 * DD, b2 + 2 * DD,
                                     h_final, nullptr, WcI, bc, logits, N);
}